// Round 1
// baseline (1265.440 us; speedup 1.0000x reference)
//
#include <hip/hip_runtime.h>
#include <math.h>

// Problem constants
#define BATCH 4
#define CIN   256
#define CCH   128      // Cout
#define HW    4096     // 64*64
#define CQK   16

__device__ __forceinline__ float fast_tanh(float x) {
    x = fminf(15.0f, fmaxf(-15.0f, x));
    float e = __expf(2.0f * x);
    return (e - 1.0f) / (e + 1.0f);
}

// ---------------------------------------------------------------------------
// 1) 3x3 conv, stride 1, pad 1. Tile: 32x32 spatial, 8 cout / block.
//    Thread: 2x2 pixels x 8 cout = 32 accumulators. Weights are block-uniform
//    -> scalar loads. x staged in LDS with halo.
// grid(4 spatial, 16 cout-groups, 4 batch), block 256
// ---------------------------------------------------------------------------
__global__ __launch_bounds__(256) void conv_kernel(
        const float* __restrict__ x, const float* __restrict__ w,
        float* __restrict__ y) {
    __shared__ float xs[4][34][36];
    const int tid = threadIdx.x;
    const int b   = blockIdx.z;
    const int co0 = blockIdx.y * 8;
    const int ty0 = (blockIdx.x >> 1) * 32, tx0 = (blockIdx.x & 1) * 32;
    const int px = (tid & 15) * 2, py = (tid >> 4) * 2;

    float acc[8][4];
#pragma unroll
    for (int i = 0; i < 8; ++i)
#pragma unroll
        for (int j = 0; j < 4; ++j) acc[i][j] = 0.f;

    for (int cb = 0; cb < CIN; cb += 4) {
        for (int idx = tid; idx < 4 * 34 * 34; idx += 256) {
            int ci = idx / 1156, r = idx % 1156, yy = r / 34, xx = r % 34;
            int gy = ty0 + yy - 1, gx = tx0 + xx - 1;
            float v = 0.f;
            if (gy >= 0 && gy < 64 && gx >= 0 && gx < 64)
                v = x[(((b << 8) + (cb + ci)) << 12) + (gy << 6) + gx];
            xs[ci][yy][xx] = v;
        }
        __syncthreads();
#pragma unroll
        for (int ci = 0; ci < 4; ++ci) {
            float win[4][4];
#pragma unroll
            for (int r = 0; r < 4; ++r) {
                float2 a  = *(const float2*)&xs[ci][py + r][px];
                float2 c2 = *(const float2*)&xs[ci][py + r][px + 2];
                win[r][0] = a.x; win[r][1] = a.y; win[r][2] = c2.x; win[r][3] = c2.y;
            }
            const float* wp = &w[(co0 * CIN + (cb + ci)) * 9];
#pragma unroll
            for (int co = 0; co < 8; ++co) {
                const float* wq = wp + co * CIN * 9;
                float w0 = wq[0], w1 = wq[1], w2 = wq[2], w3 = wq[3], w4 = wq[4],
                      w5 = wq[5], w6 = wq[6], w7 = wq[7], w8 = wq[8];
#pragma unroll
                for (int dy = 0; dy < 2; ++dy)
#pragma unroll
                    for (int dx = 0; dx < 2; ++dx) {
                        float s = win[dy + 0][dx + 0] * w0 + win[dy + 0][dx + 1] * w1 +
                                  win[dy + 0][dx + 2] * w2 + win[dy + 1][dx + 0] * w3 +
                                  win[dy + 1][dx + 1] * w4 + win[dy + 1][dx + 2] * w5 +
                                  win[dy + 2][dx + 0] * w6 + win[dy + 2][dx + 1] * w7 +
                                  win[dy + 2][dx + 2] * w8;
                        acc[co][dy * 2 + dx] += s;
                    }
            }
        }
        __syncthreads();
    }
#pragma unroll
    for (int co = 0; co < 8; ++co)
#pragma unroll
        for (int dy = 0; dy < 2; ++dy) {
            float2 o = make_float2(acc[co][dy * 2], acc[co][dy * 2 + 1]);
            *(float2*)&y[(((b << 7) + co0 + co) << 12) + ((ty0 + py + dy) << 6) + tx0 + px] = o;
        }
}

// ---------------------------------------------------------------------------
// 2) BN stats per channel -> fused scale/shift. grid(128), block 256
// ---------------------------------------------------------------------------
__global__ __launch_bounds__(256) void bn_stats_kernel(
        const float* __restrict__ y, const float* __restrict__ gamma,
        const float* __restrict__ beta, float* __restrict__ scale,
        float* __restrict__ shift) {
    const int c = blockIdx.x, tid = threadIdx.x;
    float s = 0.f, q = 0.f;
    for (int i = tid; i < BATCH * HW; i += 256) {
        float v = y[((((i >> 12) << 7) + c) << 12) + (i & 4095)];
        s += v; q += v * v;
    }
    for (int off = 32; off; off >>= 1) {
        s += __shfl_down(s, off);
        q += __shfl_down(q, off);
    }
    __shared__ float ls[4], lq[4];
    if ((tid & 63) == 0) { ls[tid >> 6] = s; lq[tid >> 6] = q; }
    __syncthreads();
    if (tid == 0) {
        float S = ls[0] + ls[1] + ls[2] + ls[3];
        float Q = lq[0] + lq[1] + lq[2] + lq[3];
        float mean = S * (1.f / 16384.f);
        float var  = Q * (1.f / 16384.f) - mean * mean;
        float rstd = rsqrtf(var + 1e-5f);
        float sc = gamma[c] * rstd;
        scale[c] = sc;
        shift[c] = beta[c] - mean * sc;
    }
}

// 3) BN apply + ReLU in place. grid(2048), block 256, float4/thread
__global__ __launch_bounds__(256) void bn_apply_kernel(
        float* __restrict__ feat, const float* __restrict__ scale,
        const float* __restrict__ shift) {
    int base = (blockIdx.x * 256 + threadIdx.x) * 4;
    int c = (base >> 12) & 127;
    float sc = scale[c], sh = shift[c];
    float4 v = *(float4*)&feat[base];
    v.x = fmaxf(fmaf(v.x, sc, sh), 0.f);
    v.y = fmaxf(fmaf(v.y, sc, sh), 0.f);
    v.z = fmaxf(fmaf(v.z, sc, sh), 0.f);
    v.w = fmaxf(fmaf(v.w, sc, sh), 0.f);
    *(float4*)&feat[base] = v;
}

// 4) zero the CAM energy buffer (B*128*128 floats). grid(64), block 256
__global__ __launch_bounds__(256) void zero_kernel(float* __restrict__ p) {
    int idx = (blockIdx.x * 256 + threadIdx.x) * 4;
    *(float4*)&p[idx] = make_float4(0.f, 0.f, 0.f, 0.f);
}

// ---------------------------------------------------------------------------
// 5) CAM energy: energy[b][c][d] = sum_n f[c,n] f[d,n], split-K (64) + atomics
// grid(64 kchunks, 4 batch), block 256, 8x8 register tile
// ---------------------------------------------------------------------------
__global__ __launch_bounds__(256, 2) void cam_energy_kernel(
        const float* __restrict__ feat, float* __restrict__ energy) {
    __shared__ float fs[128][68];
    const int b = blockIdx.y, n0 = blockIdx.x * 64, tid = threadIdx.x;
    for (int idx = tid; idx < 128 * 64; idx += 256) {
        int cc = idx >> 6, nn = idx & 63;
        fs[cc][nn] = feat[(((b << 7) + cc) << 12) + n0 + nn];
    }
    __syncthreads();
    const int cg = tid >> 4, dg = tid & 15;
    float acc[8][8];
#pragma unroll
    for (int i = 0; i < 8; ++i)
#pragma unroll
        for (int j = 0; j < 8; ++j) acc[i][j] = 0.f;
    for (int nn = 0; nn < 64; nn += 4) {
        float4 a[8], d4[8];
#pragma unroll
        for (int i = 0; i < 8; ++i) a[i] = *(const float4*)&fs[cg + 16 * i][nn];
#pragma unroll
        for (int j = 0; j < 8; ++j) d4[j] = *(const float4*)&fs[dg + 16 * j][nn];
#pragma unroll
        for (int i = 0; i < 8; ++i)
#pragma unroll
            for (int j = 0; j < 8; ++j)
                acc[i][j] += a[i].x * d4[j].x + a[i].y * d4[j].y +
                             a[i].z * d4[j].z + a[i].w * d4[j].w;
    }
#pragma unroll
    for (int i = 0; i < 8; ++i)
#pragma unroll
        for (int j = 0; j < 8; ++j)
            atomicAdd(&energy[(b << 14) + ((cg + 16 * i) << 7) + dg + 16 * j], acc[i][j]);
}

// 6) CAM attn: row-wise max, attn = tanh(max - e), in place.
// grid(128 rows, 4 batch), block 128
__global__ __launch_bounds__(128) void cam_attn_kernel(float* __restrict__ energy) {
    const int b = blockIdx.y, c = blockIdx.x, tid = threadIdx.x;
    float v = energy[(b << 14) + (c << 7) + tid];
    float m = v;
    for (int off = 32; off; off >>= 1) m = fmaxf(m, __shfl_down(m, off));
    __shared__ float mx[2];
    if ((tid & 63) == 0) mx[tid >> 6] = m;
    __syncthreads();
    float M = fmaxf(mx[0], mx[1]);
    energy[(b << 14) + (c << 7) + tid] = fast_tanh(M - v);
}

// ---------------------------------------------------------------------------
// 7) CAM out + base: out = 3*feat + g_ca * (attn @ f).
// grid(64 mtiles, 4 batch), block 256; thread tile 8c x 4m; attn staged in
// two 64-col LDS halves (keeps static LDS < 64 KB).
// ---------------------------------------------------------------------------
__global__ __launch_bounds__(256) void cam_out_kernel(
        const float* __restrict__ feat, const float* __restrict__ attn,
        const float* __restrict__ gca, float* __restrict__ out) {
    __shared__ float attn_s[128][68];
    const int b = blockIdx.y, m0 = blockIdx.x * 64, tid = threadIdx.x;
    const int cgi = tid & 15, mgi = tid >> 4;
    const int mbase = m0 + mgi * 4;
    float acc[8][4];
#pragma unroll
    for (int i = 0; i < 8; ++i)
#pragma unroll
        for (int j = 0; j < 4; ++j) acc[i][j] = 0.f;

    for (int stage = 0; stage < 2; ++stage) {
        const int d0 = stage * 64;
        __syncthreads();
        for (int idx = tid; idx < 8192; idx += 256) {
            int cc = idx >> 6, dd = idx & 63;
            attn_s[cc][dd] = attn[(b << 14) + (cc << 7) + d0 + dd];
        }
        __syncthreads();
        for (int dd = 0; dd < 64; ++dd) {
            float4 f4 = *(const float4*)&feat[(((b << 7) + d0 + dd) << 12) + mbase];
#pragma unroll
            for (int i = 0; i < 8; ++i) {
                float a = attn_s[cgi + 16 * i][dd];
                acc[i][0] += a * f4.x; acc[i][1] += a * f4.y;
                acc[i][2] += a * f4.z; acc[i][3] += a * f4.w;
            }
        }
    }
    const float g = gca[0];
#pragma unroll
    for (int i = 0; i < 8; ++i) {
        int c = cgi + 16 * i;
        float4 fv = *(const float4*)&feat[(((b << 7) + c) << 12) + mbase];
        float4 o;
        o.x = 3.f * fv.x + g * acc[i][0];
        o.y = 3.f * fv.y + g * acc[i][1];
        o.z = 3.f * fv.z + g * acc[i][2];
        o.w = 3.f * fv.w + g * acc[i][3];
        *(float4*)&out[(((b << 7) + c) << 12) + mbase] = o;
    }
}

// ---------------------------------------------------------------------------
// 8) QKV projection into one buffer: rows 0..15 q, 16..31 k, 32..159 v.
// grid(4 nchunks, 20 ogroups, 4 batch), block 256; thread: 8 rows x 4 cols.
// Weight reads are block-uniform -> scalar.
// ---------------------------------------------------------------------------
__global__ __launch_bounds__(256) void qkv_kernel(
        const float* __restrict__ feat,
        const float* __restrict__ qw, const float* __restrict__ qb,
        const float* __restrict__ kw, const float* __restrict__ kb,
        const float* __restrict__ vw, const float* __restrict__ vb,
        float* __restrict__ qkv) {
    const int b = blockIdx.z, o0 = blockIdx.y * 8;
    const int n0 = blockIdx.x * 1024 + threadIdx.x * 4;
    const float* wseg; const float* bseg; int orel;
    if (o0 < 16)      { wseg = qw; bseg = qb; orel = o0; }
    else if (o0 < 32) { wseg = kw; bseg = kb; orel = o0 - 16; }
    else              { wseg = vw; bseg = vb; orel = o0 - 32; }
    float acc[8][4];
#pragma unroll
    for (int i = 0; i < 8; ++i)
#pragma unroll
        for (int j = 0; j < 4; ++j) acc[i][j] = 0.f;
    for (int c = 0; c < CCH; ++c) {
        float4 f4 = *(const float4*)&feat[(((b << 7) + c) << 12) + n0];
#pragma unroll
        for (int oo = 0; oo < 8; ++oo) {
            float wv = wseg[((orel + oo) << 7) + c];
            acc[oo][0] += wv * f4.x; acc[oo][1] += wv * f4.y;
            acc[oo][2] += wv * f4.z; acc[oo][3] += wv * f4.w;
        }
    }
#pragma unroll
    for (int oo = 0; oo < 8; ++oo) {
        float bias = bseg[orel + oo];
        float4 o = make_float4(acc[oo][0] + bias, acc[oo][1] + bias,
                               acc[oo][2] + bias, acc[oo][3] + bias);
        *(float4*)&qkv[((b * 160 + o0 + oo) << 12) + n0] = o;
    }
}

// ---------------------------------------------------------------------------
// 9) PAM fused (flash-style, no softmax): per block (b, 128 m-tile, 1024
// n-chunk). Per 32-n subtile: S = q^T k -> tanh -> LDS; PV with 8c x 8m
// register tile; atomicAdd(g_pa * acc) into out.
// grid(4 nchunks, 32 mtiles, 4 batch), block 256
// ---------------------------------------------------------------------------
__global__ __launch_bounds__(256, 2) void pam_main_kernel(
        const float* __restrict__ qkv, const float* __restrict__ gpa,
        float* __restrict__ out) {
    __shared__ float qs[16][128];
    __shared__ float ks[16][36];
    __shared__ float vs[128][36];
    __shared__ float Ss[128][36];
    const int b = blockIdx.z, m0 = blockIdx.y * 128, nbase = blockIdx.x * 1024;
    const int tid = threadIdx.x;

    for (int idx = tid; idx < 2048; idx += 256) {
        int i = idx >> 7, m = idx & 127;
        qs[i][m] = qkv[((b * 160 + i) << 12) + m0 + m];
    }
    const int amg = tid & 31, ang = tid >> 5;   // phase A: 4m x 4n
    const int cg  = tid & 15, mg  = tid >> 4;   // phase B: 8c x 8m
    float acc[8][8];
#pragma unroll
    for (int i = 0; i < 8; ++i)
#pragma unroll
        for (int j = 0; j < 8; ++j) acc[i][j] = 0.f;

    for (int ns = 0; ns < 1024; ns += 32) {
        const int n0 = nbase + ns;
        __syncthreads();
        for (int idx = tid; idx < 512; idx += 256) {
            int i = idx >> 5, nn = idx & 31;
            ks[i][nn] = qkv[((b * 160 + 16 + i) << 12) + n0 + nn];
        }
        for (int idx = tid; idx < 4096; idx += 256) {
            int cc = idx >> 5, nn = idx & 31;
            vs[cc][nn] = qkv[((b * 160 + 32 + cc) << 12) + n0 + nn];
        }
        __syncthreads();
        // phase A: S tile + tanh -> Ss
        float S[4][4];
#pragma unroll
        for (int r = 0; r < 4; ++r)
#pragma unroll
            for (int s = 0; s < 4; ++s) S[r][s] = 0.f;
#pragma unroll
        for (int i = 0; i < 16; ++i) {
            float4 q4 = *(const float4*)&qs[i][amg << 2];
            float4 k4 = *(const float4*)&ks[i][ang << 2];
            S[0][0] += q4.x * k4.x; S[0][1] += q4.x * k4.y; S[0][2] += q4.x * k4.z; S[0][3] += q4.x * k4.w;
            S[1][0] += q4.y * k4.x; S[1][1] += q4.y * k4.y; S[1][2] += q4.y * k4.z; S[1][3] += q4.y * k4.w;
            S[2][0] += q4.z * k4.x; S[2][1] += q4.z * k4.y; S[2][2] += q4.z * k4.z; S[2][3] += q4.z * k4.w;
            S[3][0] += q4.w * k4.x; S[3][1] += q4.w * k4.y; S[3][2] += q4.w * k4.z; S[3][3] += q4.w * k4.w;
        }
#pragma unroll
        for (int r = 0; r < 4; ++r) {
            float4 t;
            t.x = fast_tanh(S[r][0]); t.y = fast_tanh(S[r][1]);
            t.z = fast_tanh(S[r][2]); t.w = fast_tanh(S[r][3]);
            *(float4*)&Ss[(amg << 2) + r][ang << 2] = t;
        }
        __syncthreads();
        // phase B: acc[c][m] += v[c][n] * attn[m][n]
        for (int nn = 0; nn < 32; nn += 4) {
            float4 v4[8], a4[8];
#pragma unroll
            for (int i = 0; i < 8; ++i) v4[i] = *(const float4*)&vs[cg + 16 * i][nn];
#pragma unroll
            for (int j = 0; j < 8; ++j) a4[j] = *(const float4*)&Ss[mg + 16 * j][nn];
#pragma unroll
            for (int i = 0; i < 8; ++i)
#pragma unroll
                for (int j = 0; j < 8; ++j)
                    acc[i][j] += v4[i].x * a4[j].x + v4[i].y * a4[j].y +
                                 v4[i].z * a4[j].z + v4[i].w * a4[j].w;
        }
    }
    const float g = gpa[0];
#pragma unroll
    for (int i = 0; i < 8; ++i) {
        int c = cg + 16 * i;
#pragma unroll
        for (int j = 0; j < 8; ++j) {
            int m = m0 + mg + 16 * j;
            atomicAdd(&out[(((b << 7) + c) << 12) + m], g * acc[i][j]);
        }
    }
}

// ---------------------------------------------------------------------------
extern "C" void kernel_launch(void* const* d_in, const int* in_sizes, int n_in,
                              void* d_out, int out_size, void* d_ws, size_t ws_size,
                              hipStream_t stream) {
    const float* x      = (const float*)d_in[0];
    const float* conv_w = (const float*)d_in[1];
    const float* bn_g   = (const float*)d_in[2];
    const float* bn_b   = (const float*)d_in[3];
    const float* q_w    = (const float*)d_in[4];
    const float* q_b    = (const float*)d_in[5];
    const float* k_w    = (const float*)d_in[6];
    const float* k_b    = (const float*)d_in[7];
    const float* v_w    = (const float*)d_in[8];
    const float* v_b    = (const float*)d_in[9];
    const float* gca    = (const float*)d_in[10];
    const float* gpa    = (const float*)d_in[11];
    float* out = (float*)d_out;

    float* ws     = (float*)d_ws;
    float* feat   = ws;                 // 2,097,152 floats (y, then feat in place)
    float* qkvb   = ws + 2097152;       // 2,621,440 floats
    float* energy = ws + 4718592;       // 65,536 floats (energy -> attn in place)
    float* scale  = ws + 4784128;       // 128
    float* shift  = ws + 4784256;       // 128

    conv_kernel<<<dim3(4, 16, 4), 256, 0, stream>>>(x, conv_w, feat);
    bn_stats_kernel<<<128, 256, 0, stream>>>(feat, bn_g, bn_b, scale, shift);
    bn_apply_kernel<<<2048, 256, 0, stream>>>(feat, scale, shift);
    zero_kernel<<<64, 256, 0, stream>>>(energy);
    cam_energy_kernel<<<dim3(64, 4), 256, 0, stream>>>(feat, energy);
    cam_attn_kernel<<<dim3(128, 4), 128, 0, stream>>>(energy);
    qkv_kernel<<<dim3(4, 20, 4), 256, 0, stream>>>(feat, q_w, q_b, k_w, k_b, v_w, v_b, qkvb);
    cam_out_kernel<<<dim3(64, 4), 256, 0, stream>>>(feat, energy, gca, out);
    pam_main_kernel<<<dim3(4, 32, 4), 256, 0, stream>>>(qkvb, gpa, out);
}

// Round 2
// 665.006 us; speedup vs baseline: 1.9029x; 1.9029x over previous
//
#include <hip/hip_runtime.h>
#include <math.h>

// Problem constants
#define BATCH 4
#define CIN   256
#define CCH   128      // Cout
#define HW    4096     // 64*64
#define CQK   16

using short8  = __attribute__((ext_vector_type(8))) short;
using floatx4 = __attribute__((ext_vector_type(4))) float;

__device__ __forceinline__ float fast_tanh(float x) {
    x = fminf(15.0f, fmaxf(-15.0f, x));
    float e = __expf(2.0f * x);
    return (e - 1.0f) / (e + 1.0f);
}

__device__ __forceinline__ unsigned short f2bf(float f) {
    unsigned u = __float_as_uint(f);
    u += 0x7fff + ((u >> 16) & 1);   // RNE
    return (unsigned short)(u >> 16);
}

// ---------------------------------------------------------------------------
// 1a) Weight prep: w[co][ci][ky][kx] fp32 -> Wb[co][tap][ci] bf16
//     (tap-major K ordering so each tap is a clean GEMM over ci)
// ---------------------------------------------------------------------------
__global__ __launch_bounds__(256) void conv_prep_kernel(
        const float* __restrict__ w, unsigned short* __restrict__ Wb) {
    int o = blockIdx.x * 256 + threadIdx.x;          // o < 128*9*256 = 294912
    int co = o / 2304;
    int rem = o - co * 2304;
    int tap = rem >> 8;
    int ci  = rem & 255;
    Wb[o] = f2bf(w[co * 2304 + ci * 9 + tap]);
}

// ---------------------------------------------------------------------------
// 1b) Conv as implicit GEMM, bf16 MFMA 16x16x32.
//     Block: 128 co x 32 px (half row of one (b,y)).  Grid (2, 64, 4) = 512.
//     4 waves, wave tile 32co x 32px: 2 A-frags (global, L2-hot) +
//     2 B-frags (LDS, xor-swizzled) + 4 MFMA per 32-k chunk; 72 chunks.
//     LDS: xs[3][34][256] bf16 transposed (px-major rows of ci), 52 KB.
// ---------------------------------------------------------------------------
__global__ __launch_bounds__(256, 2) void conv_mfma_kernel(
        const float* __restrict__ x, const unsigned short* __restrict__ Wb,
        float* __restrict__ y) {
    __shared__ unsigned short xs[3 * 34 * 256];
    const int tid  = threadIdx.x;
    const int x0   = blockIdx.x * 32;
    const int yrow = blockIdx.y;
    const int b    = blockIdx.z;

    // ---- stage x rows (y-1, y, y+1), 256 ci, 34 px halo, bf16, swizzled ----
    for (int e = tid; e < 768 * 34; e += 256) {
        int p  = e / 34;             // (ky, ci) pair
        int px = e - p * 34;
        int ky = p >> 8, ci = p & 255;
        int gy = yrow + ky - 1;
        int gx = x0 - 1 + px;
        float v = 0.f;
        if (gy >= 0 && gy < 64 && gx >= 0 && gx < 64)
            v = x[(((b << 8) + ci) << 12) + (gy << 6) + gx];
        int c16s = (ci >> 3) ^ (px & 7);
        xs[(ky * 34 + px) * 256 + (c16s << 3) + (ci & 7)] = f2bf(v);
    }
    __syncthreads();

    const int wv   = tid >> 6;        // wave id: co base = wv*32
    const int lane = tid & 63;
    const int l15  = lane & 15;
    const int quad = lane >> 4;

    floatx4 acc[2][2];
#pragma unroll
    for (int i = 0; i < 2; ++i)
#pragma unroll
        for (int j = 0; j < 2; ++j) acc[i][j] = (floatx4){0.f, 0.f, 0.f, 0.f};

    const int coA0 = (wv * 32 + l15) * 9;        // co rows for A frag 0
    const int coA1 = (wv * 32 + 16 + l15) * 9;   // A frag 1

#pragma unroll
    for (int ky = 0; ky < 3; ++ky) {
#pragma unroll
        for (int kx = 0; kx < 3; ++kx) {
            const int tap = ky * 3 + kx;
            const int pxn0 = l15 + kx;           // n-sub 0 input px
            const int pxn1 = 16 + l15 + kx;      // n-sub 1
            const int rb0 = (ky * 34 + pxn0) * 256;
            const int rb1 = (ky * 34 + pxn1) * 256;
            const int k0s = pxn0 & 7, k1s = pxn1 & 7;
            for (int cc = 0; cc < 8; ++cc) {
                const int ci0 = cc * 32;
                short8 a0 = *(const short8*)(Wb + (coA0 + tap) * 256 + ci0 + quad * 8);
                short8 a1 = *(const short8*)(Wb + (coA1 + tap) * 256 + ci0 + quad * 8);
                int c16 = (ci0 >> 3) + quad;
                short8 b0 = *(const short8*)&xs[rb0 + ((c16 ^ k0s) << 3)];
                short8 b1 = *(const short8*)&xs[rb1 + ((c16 ^ k1s) << 3)];
                acc[0][0] = __builtin_amdgcn_mfma_f32_16x16x32_bf16(a0, b0, acc[0][0], 0, 0, 0);
                acc[0][1] = __builtin_amdgcn_mfma_f32_16x16x32_bf16(a0, b1, acc[0][1], 0, 0, 0);
                acc[1][0] = __builtin_amdgcn_mfma_f32_16x16x32_bf16(a1, b0, acc[1][0], 0, 0, 0);
                acc[1][1] = __builtin_amdgcn_mfma_f32_16x16x32_bf16(a1, b1, acc[1][1], 0, 0, 0);
            }
        }
    }

    // ---- epilogue: C/D layout col=lane&15 (px), row=quad*4+reg (co) ----
#pragma unroll
    for (int ms = 0; ms < 2; ++ms)
#pragma unroll
        for (int ns = 0; ns < 2; ++ns) {
            int px = x0 + ns * 16 + l15;
#pragma unroll
            for (int r = 0; r < 4; ++r) {
                int co = wv * 32 + ms * 16 + quad * 4 + r;
                y[(((b << 7) + co) << 12) + (yrow << 6) + px] = acc[ms][ns][r];
            }
        }
}

// ---------------------------------------------------------------------------
// 2) BN stats per channel -> fused scale/shift. grid(128), block 256
// ---------------------------------------------------------------------------
__global__ __launch_bounds__(256) void bn_stats_kernel(
        const float* __restrict__ y, const float* __restrict__ gamma,
        const float* __restrict__ beta, float* __restrict__ scale,
        float* __restrict__ shift) {
    const int c = blockIdx.x, tid = threadIdx.x;
    float s = 0.f, q = 0.f;
    for (int i = tid; i < BATCH * HW; i += 256) {
        float v = y[((((i >> 12) << 7) + c) << 12) + (i & 4095)];
        s += v; q += v * v;
    }
    for (int off = 32; off; off >>= 1) {
        s += __shfl_down(s, off);
        q += __shfl_down(q, off);
    }
    __shared__ float ls[4], lq[4];
    if ((tid & 63) == 0) { ls[tid >> 6] = s; lq[tid >> 6] = q; }
    __syncthreads();
    if (tid == 0) {
        float S = ls[0] + ls[1] + ls[2] + ls[3];
        float Q = lq[0] + lq[1] + lq[2] + lq[3];
        float mean = S * (1.f / 16384.f);
        float var  = Q * (1.f / 16384.f) - mean * mean;
        float rstd = rsqrtf(var + 1e-5f);
        float sc = gamma[c] * rstd;
        scale[c] = sc;
        shift[c] = beta[c] - mean * sc;
    }
}

// 3) BN apply + ReLU in place. grid(2048), block 256, float4/thread
__global__ __launch_bounds__(256) void bn_apply_kernel(
        float* __restrict__ feat, const float* __restrict__ scale,
        const float* __restrict__ shift) {
    int base = (blockIdx.x * 256 + threadIdx.x) * 4;
    int c = (base >> 12) & 127;
    float sc = scale[c], sh = shift[c];
    float4 v = *(float4*)&feat[base];
    v.x = fmaxf(fmaf(v.x, sc, sh), 0.f);
    v.y = fmaxf(fmaf(v.y, sc, sh), 0.f);
    v.z = fmaxf(fmaf(v.z, sc, sh), 0.f);
    v.w = fmaxf(fmaf(v.w, sc, sh), 0.f);
    *(float4*)&feat[base] = v;
}

// 4) zero the CAM energy buffer (B*128*128 floats). grid(64), block 256
__global__ __launch_bounds__(256) void zero_kernel(float* __restrict__ p) {
    int idx = (blockIdx.x * 256 + threadIdx.x) * 4;
    *(float4*)&p[idx] = make_float4(0.f, 0.f, 0.f, 0.f);
}

// ---------------------------------------------------------------------------
// 5) CAM energy: energy[b][c][d] = sum_n f[c,n] f[d,n], split-K (64) + atomics
// grid(64 kchunks, 4 batch), block 256, 8x8 register tile
// ---------------------------------------------------------------------------
__global__ __launch_bounds__(256, 2) void cam_energy_kernel(
        const float* __restrict__ feat, float* __restrict__ energy) {
    __shared__ float fs[128][68];
    const int b = blockIdx.y, n0 = blockIdx.x * 64, tid = threadIdx.x;
    for (int idx = tid; idx < 128 * 64; idx += 256) {
        int cc = idx >> 6, nn = idx & 63;
        fs[cc][nn] = feat[(((b << 7) + cc) << 12) + n0 + nn];
    }
    __syncthreads();
    const int cg = tid >> 4, dg = tid & 15;
    float acc[8][8];
#pragma unroll
    for (int i = 0; i < 8; ++i)
#pragma unroll
        for (int j = 0; j < 8; ++j) acc[i][j] = 0.f;
    for (int nn = 0; nn < 64; nn += 4) {
        float4 a[8], d4[8];
#pragma unroll
        for (int i = 0; i < 8; ++i) a[i] = *(const float4*)&fs[cg + 16 * i][nn];
#pragma unroll
        for (int j = 0; j < 8; ++j) d4[j] = *(const float4*)&fs[dg + 16 * j][nn];
#pragma unroll
        for (int i = 0; i < 8; ++i)
#pragma unroll
            for (int j = 0; j < 8; ++j)
                acc[i][j] += a[i].x * d4[j].x + a[i].y * d4[j].y +
                             a[i].z * d4[j].z + a[i].w * d4[j].w;
    }
#pragma unroll
    for (int i = 0; i < 8; ++i)
#pragma unroll
        for (int j = 0; j < 8; ++j)
            atomicAdd(&energy[(b << 14) + ((cg + 16 * i) << 7) + dg + 16 * j], acc[i][j]);
}

// 6) CAM attn: row-wise max, attn = tanh(max - e), in place.
// grid(128 rows, 4 batch), block 128
__global__ __launch_bounds__(128) void cam_attn_kernel(float* __restrict__ energy) {
    const int b = blockIdx.y, c = blockIdx.x, tid = threadIdx.x;
    float v = energy[(b << 14) + (c << 7) + tid];
    float m = v;
    for (int off = 32; off; off >>= 1) m = fmaxf(m, __shfl_down(m, off));
    __shared__ float mx[2];
    if ((tid & 63) == 0) mx[tid >> 6] = m;
    __syncthreads();
    float M = fmaxf(mx[0], mx[1]);
    energy[(b << 14) + (c << 7) + tid] = fast_tanh(M - v);
}

// ---------------------------------------------------------------------------
// 7) CAM out + base: out = 3*feat + g_ca * (attn @ f).
// grid(64 mtiles, 4 batch), block 256; thread tile 8c x 4m
// ---------------------------------------------------------------------------
__global__ __launch_bounds__(256) void cam_out_kernel(
        const float* __restrict__ feat, const float* __restrict__ attn,
        const float* __restrict__ gca, float* __restrict__ out) {
    __shared__ float attn_s[128][68];
    const int b = blockIdx.y, m0 = blockIdx.x * 64, tid = threadIdx.x;
    const int cgi = tid & 15, mgi = tid >> 4;
    const int mbase = m0 + mgi * 4;
    float acc[8][4];
#pragma unroll
    for (int i = 0; i < 8; ++i)
#pragma unroll
        for (int j = 0; j < 4; ++j) acc[i][j] = 0.f;

    for (int stage = 0; stage < 2; ++stage) {
        const int d0 = stage * 64;
        __syncthreads();
        for (int idx = tid; idx < 8192; idx += 256) {
            int cc = idx >> 6, dd = idx & 63;
            attn_s[cc][dd] = attn[(b << 14) + (cc << 7) + d0 + dd];
        }
        __syncthreads();
        for (int dd = 0; dd < 64; ++dd) {
            float4 f4 = *(const float4*)&feat[(((b << 7) + d0 + dd) << 12) + mbase];
#pragma unroll
            for (int i = 0; i < 8; ++i) {
                float a = attn_s[cgi + 16 * i][dd];
                acc[i][0] += a * f4.x; acc[i][1] += a * f4.y;
                acc[i][2] += a * f4.z; acc[i][3] += a * f4.w;
            }
        }
    }
    const float g = gca[0];
#pragma unroll
    for (int i = 0; i < 8; ++i) {
        int c = cgi + 16 * i;
        float4 fv = *(const float4*)&feat[(((b << 7) + c) << 12) + mbase];
        float4 o;
        o.x = 3.f * fv.x + g * acc[i][0];
        o.y = 3.f * fv.y + g * acc[i][1];
        o.z = 3.f * fv.z + g * acc[i][2];
        o.w = 3.f * fv.w + g * acc[i][3];
        *(float4*)&out[(((b << 7) + c) << 12) + mbase] = o;
    }
}

// ---------------------------------------------------------------------------
// 8) QKV projection: rows 0..15 q, 16..31 k, 32..159 v.
// grid(4 nchunks, 20 ogroups, 4 batch), block 256; thread: 8 rows x 4 cols.
// ---------------------------------------------------------------------------
__global__ __launch_bounds__(256) void qkv_kernel(
        const float* __restrict__ feat,
        const float* __restrict__ qw, const float* __restrict__ qb,
        const float* __restrict__ kw, const float* __restrict__ kb,
        const float* __restrict__ vw, const float* __restrict__ vb,
        float* __restrict__ qkv) {
    const int b = blockIdx.z, o0 = blockIdx.y * 8;
    const int n0 = blockIdx.x * 1024 + threadIdx.x * 4;
    const float* wseg; const float* bseg; int orel;
    if (o0 < 16)      { wseg = qw; bseg = qb; orel = o0; }
    else if (o0 < 32) { wseg = kw; bseg = kb; orel = o0 - 16; }
    else              { wseg = vw; bseg = vb; orel = o0 - 32; }
    float acc[8][4];
#pragma unroll
    for (int i = 0; i < 8; ++i)
#pragma unroll
        for (int j = 0; j < 4; ++j) acc[i][j] = 0.f;
    for (int c = 0; c < CCH; ++c) {
        float4 f4 = *(const float4*)&feat[(((b << 7) + c) << 12) + n0];
#pragma unroll
        for (int oo = 0; oo < 8; ++oo) {
            float wv = wseg[((orel + oo) << 7) + c];
            acc[oo][0] += wv * f4.x; acc[oo][1] += wv * f4.y;
            acc[oo][2] += wv * f4.z; acc[oo][3] += wv * f4.w;
        }
    }
#pragma unroll
    for (int oo = 0; oo < 8; ++oo) {
        float bias = bseg[orel + oo];
        float4 o = make_float4(acc[oo][0] + bias, acc[oo][1] + bias,
                               acc[oo][2] + bias, acc[oo][3] + bias);
        *(float4*)&qkv[((b * 160 + o0 + oo) << 12) + n0] = o;
    }
}

// ---------------------------------------------------------------------------
// 9) PAM fused (flash-style, no softmax). grid(4, 32, 4), block 256
// ---------------------------------------------------------------------------
__global__ __launch_bounds__(256, 2) void pam_main_kernel(
        const float* __restrict__ qkv, const float* __restrict__ gpa,
        float* __restrict__ out) {
    __shared__ float qs[16][128];
    __shared__ float ks[16][36];
    __shared__ float vs[128][36];
    __shared__ float Ss[128][36];
    const int b = blockIdx.z, m0 = blockIdx.y * 128, nbase = blockIdx.x * 1024;
    const int tid = threadIdx.x;

    for (int idx = tid; idx < 2048; idx += 256) {
        int i = idx >> 7, m = idx & 127;
        qs[i][m] = qkv[((b * 160 + i) << 12) + m0 + m];
    }
    const int amg = tid & 31, ang = tid >> 5;   // phase A: 4m x 4n
    const int cg  = tid & 15, mg  = tid >> 4;   // phase B: 8c x 8m
    float acc[8][8];
#pragma unroll
    for (int i = 0; i < 8; ++i)
#pragma unroll
        for (int j = 0; j < 8; ++j) acc[i][j] = 0.f;

    for (int ns = 0; ns < 1024; ns += 32) {
        const int n0 = nbase + ns;
        __syncthreads();
        for (int idx = tid; idx < 512; idx += 256) {
            int i = idx >> 5, nn = idx & 31;
            ks[i][nn] = qkv[((b * 160 + 16 + i) << 12) + n0 + nn];
        }
        for (int idx = tid; idx < 4096; idx += 256) {
            int cc = idx >> 5, nn = idx & 31;
            vs[cc][nn] = qkv[((b * 160 + 32 + cc) << 12) + n0 + nn];
        }
        __syncthreads();
        float S[4][4];
#pragma unroll
        for (int r = 0; r < 4; ++r)
#pragma unroll
            for (int s = 0; s < 4; ++s) S[r][s] = 0.f;
#pragma unroll
        for (int i = 0; i < 16; ++i) {
            float4 q4 = *(const float4*)&qs[i][amg << 2];
            float4 k4 = *(const float4*)&ks[i][ang << 2];
            S[0][0] += q4.x * k4.x; S[0][1] += q4.x * k4.y; S[0][2] += q4.x * k4.z; S[0][3] += q4.x * k4.w;
            S[1][0] += q4.y * k4.x; S[1][1] += q4.y * k4.y; S[1][2] += q4.y * k4.z; S[1][3] += q4.y * k4.w;
            S[2][0] += q4.z * k4.x; S[2][1] += q4.z * k4.y; S[2][2] += q4.z * k4.z; S[2][3] += q4.z * k4.w;
            S[3][0] += q4.w * k4.x; S[3][1] += q4.w * k4.y; S[3][2] += q4.w * k4.z; S[3][3] += q4.w * k4.w;
        }
#pragma unroll
        for (int r = 0; r < 4; ++r) {
            float4 t;
            t.x = fast_tanh(S[r][0]); t.y = fast_tanh(S[r][1]);
            t.z = fast_tanh(S[r][2]); t.w = fast_tanh(S[r][3]);
            *(float4*)&Ss[(amg << 2) + r][ang << 2] = t;
        }
        __syncthreads();
        for (int nn = 0; nn < 32; nn += 4) {
            float4 v4[8], a4[8];
#pragma unroll
            for (int i = 0; i < 8; ++i) v4[i] = *(const float4*)&vs[cg + 16 * i][nn];
#pragma unroll
            for (int j = 0; j < 8; ++j) a4[j] = *(const float4*)&Ss[mg + 16 * j][nn];
#pragma unroll
            for (int i = 0; i < 8; ++i)
#pragma unroll
                for (int j = 0; j < 8; ++j)
                    acc[i][j] += v4[i].x * a4[j].x + v4[i].y * a4[j].y +
                                 v4[i].z * a4[j].z + v4[i].w * a4[j].w;
        }
    }
    const float g = gpa[0];
#pragma unroll
    for (int i = 0; i < 8; ++i) {
        int c = cg + 16 * i;
#pragma unroll
        for (int j = 0; j < 8; ++j) {
            int m = m0 + mg + 16 * j;
            atomicAdd(&out[(((b << 7) + c) << 12) + m], g * acc[i][j]);
        }
    }
}

// ---------------------------------------------------------------------------
extern "C" void kernel_launch(void* const* d_in, const int* in_sizes, int n_in,
                              void* d_out, int out_size, void* d_ws, size_t ws_size,
                              hipStream_t stream) {
    const float* x      = (const float*)d_in[0];
    const float* conv_w = (const float*)d_in[1];
    const float* bn_g   = (const float*)d_in[2];
    const float* bn_b   = (const float*)d_in[3];
    const float* q_w    = (const float*)d_in[4];
    const float* q_b    = (const float*)d_in[5];
    const float* k_w    = (const float*)d_in[6];
    const float* k_b    = (const float*)d_in[7];
    const float* v_w    = (const float*)d_in[8];
    const float* v_b    = (const float*)d_in[9];
    const float* gca    = (const float*)d_in[10];
    const float* gpa    = (const float*)d_in[11];
    float* out = (float*)d_out;

    float* ws     = (float*)d_ws;
    float* feat   = ws;                 // 2,097,152 floats (conv out, then feat in place)
    float* qkvb   = ws + 2097152;       // 2,621,440 floats
    float* energy = ws + 4718592;       // 65,536 floats
    float* scale  = ws + 4784128;       // 128
    float* shift  = ws + 4784256;       // 128
    unsigned short* Wb = (unsigned short*)(ws + 4784384);  // 294,912 bf16

    conv_prep_kernel<<<1152, 256, 0, stream>>>(conv_w, Wb);
    conv_mfma_kernel<<<dim3(2, 64, 4), 256, 0, stream>>>(x, Wb, feat);
    bn_stats_kernel<<<128, 256, 0, stream>>>(feat, bn_g, bn_b, scale, shift);
    bn_apply_kernel<<<2048, 256, 0, stream>>>(feat, scale, shift);
    zero_kernel<<<64, 256, 0, stream>>>(energy);
    cam_energy_kernel<<<dim3(64, 4), 256, 0, stream>>>(feat, energy);
    cam_attn_kernel<<<dim3(128, 4), 128, 0, stream>>>(energy);
    qkv_kernel<<<dim3(4, 20, 4), 256, 0, stream>>>(feat, q_w, q_b, k_w, k_b, v_w, v_b, qkvb);
    cam_out_kernel<<<dim3(64, 4), 256, 0, stream>>>(feat, energy, gca, out);
    pam_main_kernel<<<dim3(4, 32, 4), 256, 0, stream>>>(qkvb, gpa, out);
}

// Round 3
// 344.253 us; speedup vs baseline: 3.6759x; 1.9317x over previous
//
#include <hip/hip_runtime.h>
#include <math.h>

// Problem constants
#define BATCH 4
#define CIN   256
#define CCH   128      // Cout
#define HW    4096     // 64*64
#define CQK   16

using short8   = __attribute__((ext_vector_type(8))) short;
using floatx4  = __attribute__((ext_vector_type(4))) float;
using floatx16 = __attribute__((ext_vector_type(16))) float;

__device__ __forceinline__ float fast_tanh(float x) {
    // 1 - 2/(e^{2x}+1): saturates correctly for |x| large (inf -> 1, 0 -> -1)
    float e = __expf(2.0f * x);
    return 1.0f - __fdividef(2.0f, e + 1.0f);
}

__device__ __forceinline__ unsigned short f2bf(float f) {
    unsigned u = __float_as_uint(f);
    u += 0x7fff + ((u >> 16) & 1);   // RNE
    return (unsigned short)(u >> 16);
}

// ---------------------------------------------------------------------------
// 1a) Weight prep: w[co][ci][ky][kx] fp32 -> Wb[co][tap][ci] bf16
// ---------------------------------------------------------------------------
__global__ __launch_bounds__(256) void conv_prep_kernel(
        const float* __restrict__ w, unsigned short* __restrict__ Wb) {
    int o = blockIdx.x * 256 + threadIdx.x;          // o < 128*9*256 = 294912
    int co = o / 2304;
    int rem = o - co * 2304;
    int tap = rem >> 8;
    int ci  = rem & 255;
    Wb[o] = f2bf(w[co * 2304 + ci * 9 + tap]);
}

// ---------------------------------------------------------------------------
// 1b) Conv as implicit GEMM, bf16 MFMA 16x16x32. (unchanged from R2)
// ---------------------------------------------------------------------------
__global__ __launch_bounds__(256, 2) void conv_mfma_kernel(
        const float* __restrict__ x, const unsigned short* __restrict__ Wb,
        float* __restrict__ y) {
    __shared__ unsigned short xs[3 * 34 * 256];
    const int tid  = threadIdx.x;
    const int x0   = blockIdx.x * 32;
    const int yrow = blockIdx.y;
    const int b    = blockIdx.z;

    for (int e = tid; e < 768 * 34; e += 256) {
        int p  = e / 34;
        int px = e - p * 34;
        int ky = p >> 8, ci = p & 255;
        int gy = yrow + ky - 1;
        int gx = x0 - 1 + px;
        float v = 0.f;
        if (gy >= 0 && gy < 64 && gx >= 0 && gx < 64)
            v = x[(((b << 8) + ci) << 12) + (gy << 6) + gx];
        int c16s = (ci >> 3) ^ (px & 7);
        xs[(ky * 34 + px) * 256 + (c16s << 3) + (ci & 7)] = f2bf(v);
    }
    __syncthreads();

    const int wv   = tid >> 6;
    const int lane = tid & 63;
    const int l15  = lane & 15;
    const int quad = lane >> 4;

    floatx4 acc[2][2];
#pragma unroll
    for (int i = 0; i < 2; ++i)
#pragma unroll
        for (int j = 0; j < 2; ++j) acc[i][j] = (floatx4){0.f, 0.f, 0.f, 0.f};

    const int coA0 = (wv * 32 + l15) * 9;
    const int coA1 = (wv * 32 + 16 + l15) * 9;

#pragma unroll
    for (int ky = 0; ky < 3; ++ky) {
#pragma unroll
        for (int kx = 0; kx < 3; ++kx) {
            const int tap = ky * 3 + kx;
            const int pxn0 = l15 + kx;
            const int pxn1 = 16 + l15 + kx;
            const int rb0 = (ky * 34 + pxn0) * 256;
            const int rb1 = (ky * 34 + pxn1) * 256;
            const int k0s = pxn0 & 7, k1s = pxn1 & 7;
            for (int cc = 0; cc < 8; ++cc) {
                const int ci0 = cc * 32;
                short8 a0 = *(const short8*)(Wb + (coA0 + tap) * 256 + ci0 + quad * 8);
                short8 a1 = *(const short8*)(Wb + (coA1 + tap) * 256 + ci0 + quad * 8);
                int c16 = (ci0 >> 3) + quad;
                short8 b0 = *(const short8*)&xs[rb0 + ((c16 ^ k0s) << 3)];
                short8 b1 = *(const short8*)&xs[rb1 + ((c16 ^ k1s) << 3)];
                acc[0][0] = __builtin_amdgcn_mfma_f32_16x16x32_bf16(a0, b0, acc[0][0], 0, 0, 0);
                acc[0][1] = __builtin_amdgcn_mfma_f32_16x16x32_bf16(a0, b1, acc[0][1], 0, 0, 0);
                acc[1][0] = __builtin_amdgcn_mfma_f32_16x16x32_bf16(a1, b0, acc[1][0], 0, 0, 0);
                acc[1][1] = __builtin_amdgcn_mfma_f32_16x16x32_bf16(a1, b1, acc[1][1], 0, 0, 0);
            }
        }
    }

#pragma unroll
    for (int ms = 0; ms < 2; ++ms)
#pragma unroll
        for (int ns = 0; ns < 2; ++ns) {
            int px = x0 + ns * 16 + l15;
#pragma unroll
            for (int r = 0; r < 4; ++r) {
                int co = wv * 32 + ms * 16 + quad * 4 + r;
                y[(((b << 7) + co) << 12) + (yrow << 6) + px] = acc[ms][ns][r];
            }
        }
}

// ---------------------------------------------------------------------------
// 2) BN stats per channel -> fused scale/shift. grid(128), block 256
// ---------------------------------------------------------------------------
__global__ __launch_bounds__(256) void bn_stats_kernel(
        const float* __restrict__ y, const float* __restrict__ gamma,
        const float* __restrict__ beta, float* __restrict__ scale,
        float* __restrict__ shift) {
    const int c = blockIdx.x, tid = threadIdx.x;
    float s = 0.f, q = 0.f;
    for (int i = tid; i < BATCH * HW; i += 256) {
        float v = y[((((i >> 12) << 7) + c) << 12) + (i & 4095)];
        s += v; q += v * v;
    }
    for (int off = 32; off; off >>= 1) {
        s += __shfl_down(s, off);
        q += __shfl_down(q, off);
    }
    __shared__ float ls[4], lq[4];
    if ((tid & 63) == 0) { ls[tid >> 6] = s; lq[tid >> 6] = q; }
    __syncthreads();
    if (tid == 0) {
        float S = ls[0] + ls[1] + ls[2] + ls[3];
        float Q = lq[0] + lq[1] + lq[2] + lq[3];
        float mean = S * (1.f / 16384.f);
        float var  = Q * (1.f / 16384.f) - mean * mean;
        float rstd = rsqrtf(var + 1e-5f);
        float sc = gamma[c] * rstd;
        scale[c] = sc;
        shift[c] = beta[c] - mean * sc;
    }
}

// 3) BN apply + ReLU in place. grid(2048), block 256, float4/thread
__global__ __launch_bounds__(256) void bn_apply_kernel(
        float* __restrict__ feat, const float* __restrict__ scale,
        const float* __restrict__ shift) {
    int base = (blockIdx.x * 256 + threadIdx.x) * 4;
    int c = (base >> 12) & 127;
    float sc = scale[c], sh = shift[c];
    float4 v = *(float4*)&feat[base];
    v.x = fmaxf(fmaf(v.x, sc, sh), 0.f);
    v.y = fmaxf(fmaf(v.y, sc, sh), 0.f);
    v.z = fmaxf(fmaf(v.z, sc, sh), 0.f);
    v.w = fmaxf(fmaf(v.w, sc, sh), 0.f);
    *(float4*)&feat[base] = v;
}

// 4) zero the CAM energy buffer. grid(64), block 256
__global__ __launch_bounds__(256) void zero_kernel(float* __restrict__ p) {
    int idx = (blockIdx.x * 256 + threadIdx.x) * 4;
    *(float4*)&p[idx] = make_float4(0.f, 0.f, 0.f, 0.f);
}

// ---------------------------------------------------------------------------
// 5) CAM energy: split-K (64) + atomics. grid(64, 4), block 256
// ---------------------------------------------------------------------------
__global__ __launch_bounds__(256, 2) void cam_energy_kernel(
        const float* __restrict__ feat, float* __restrict__ energy) {
    __shared__ float fs[128][68];
    const int b = blockIdx.y, n0 = blockIdx.x * 64, tid = threadIdx.x;
    for (int idx = tid; idx < 128 * 64; idx += 256) {
        int cc = idx >> 6, nn = idx & 63;
        fs[cc][nn] = feat[(((b << 7) + cc) << 12) + n0 + nn];
    }
    __syncthreads();
    const int cg = tid >> 4, dg = tid & 15;
    float acc[8][8];
#pragma unroll
    for (int i = 0; i < 8; ++i)
#pragma unroll
        for (int j = 0; j < 8; ++j) acc[i][j] = 0.f;
    for (int nn = 0; nn < 64; nn += 4) {
        float4 a[8], d4[8];
#pragma unroll
        for (int i = 0; i < 8; ++i) a[i] = *(const float4*)&fs[cg + 16 * i][nn];
#pragma unroll
        for (int j = 0; j < 8; ++j) d4[j] = *(const float4*)&fs[dg + 16 * j][nn];
#pragma unroll
        for (int i = 0; i < 8; ++i)
#pragma unroll
            for (int j = 0; j < 8; ++j)
                acc[i][j] += a[i].x * d4[j].x + a[i].y * d4[j].y +
                             a[i].z * d4[j].z + a[i].w * d4[j].w;
    }
#pragma unroll
    for (int i = 0; i < 8; ++i)
#pragma unroll
        for (int j = 0; j < 8; ++j)
            atomicAdd(&energy[(b << 14) + ((cg + 16 * i) << 7) + dg + 16 * j], acc[i][j]);
}

// 6) CAM attn: attn = tanh(rowmax - e), in place. grid(128, 4), block 128
__global__ __launch_bounds__(128) void cam_attn_kernel(float* __restrict__ energy) {
    const int b = blockIdx.y, c = blockIdx.x, tid = threadIdx.x;
    float v = energy[(b << 14) + (c << 7) + tid];
    float m = v;
    for (int off = 32; off; off >>= 1) m = fmaxf(m, __shfl_down(m, off));
    __shared__ float mx[2];
    if ((tid & 63) == 0) mx[tid >> 6] = m;
    __syncthreads();
    float M = fmaxf(mx[0], mx[1]);
    energy[(b << 14) + (c << 7) + tid] = fast_tanh(M - v);
}

// ---------------------------------------------------------------------------
// 7) CAM out + base: out = 3*feat + g_ca * (attn @ f). grid(64, 4), block 256
// ---------------------------------------------------------------------------
__global__ __launch_bounds__(256) void cam_out_kernel(
        const float* __restrict__ feat, const float* __restrict__ attn,
        const float* __restrict__ gca, float* __restrict__ out) {
    __shared__ float attn_s[128][68];
    const int b = blockIdx.y, m0 = blockIdx.x * 64, tid = threadIdx.x;
    const int cgi = tid & 15, mgi = tid >> 4;
    const int mbase = m0 + mgi * 4;
    float acc[8][4];
#pragma unroll
    for (int i = 0; i < 8; ++i)
#pragma unroll
        for (int j = 0; j < 4; ++j) acc[i][j] = 0.f;

    for (int stage = 0; stage < 2; ++stage) {
        const int d0 = stage * 64;
        __syncthreads();
        for (int idx = tid; idx < 8192; idx += 256) {
            int cc = idx >> 6, dd = idx & 63;
            attn_s[cc][dd] = attn[(b << 14) + (cc << 7) + d0 + dd];
        }
        __syncthreads();
        for (int dd = 0; dd < 64; ++dd) {
            float4 f4 = *(const float4*)&feat[(((b << 7) + d0 + dd) << 12) + mbase];
#pragma unroll
            for (int i = 0; i < 8; ++i) {
                float a = attn_s[cgi + 16 * i][dd];
                acc[i][0] += a * f4.x; acc[i][1] += a * f4.y;
                acc[i][2] += a * f4.z; acc[i][3] += a * f4.w;
            }
        }
    }
    const float g = gca[0];
#pragma unroll
    for (int i = 0; i < 8; ++i) {
        int c = cgi + 16 * i;
        float4 fv = *(const float4*)&feat[(((b << 7) + c) << 12) + mbase];
        float4 o;
        o.x = 3.f * fv.x + g * acc[i][0];
        o.y = 3.f * fv.y + g * acc[i][1];
        o.z = 3.f * fv.z + g * acc[i][2];
        o.w = 3.f * fv.w + g * acc[i][3];
        *(float4*)&out[(((b << 7) + c) << 12) + mbase] = o;
    }
}

// ---------------------------------------------------------------------------
// 8) QKV projection -> bf16 MFMA layouts:
//    qT[b][m][16] (A/B frag-friendly, 8 consecutive k per lane-half)
//    kT[b][n][16], vB[b][c][n] row-major.
// grid(4 nchunks, 20 ogroups, 4 batch), block 256; thread: 8 rows x 4 cols.
// ---------------------------------------------------------------------------
__global__ __launch_bounds__(256) void qkv_kernel(
        const float* __restrict__ feat,
        const float* __restrict__ qw, const float* __restrict__ qb,
        const float* __restrict__ kw, const float* __restrict__ kb,
        const float* __restrict__ vw, const float* __restrict__ vb,
        unsigned short* __restrict__ qT, unsigned short* __restrict__ kT,
        unsigned short* __restrict__ vB) {
    const int b = blockIdx.z, o0 = blockIdx.y * 8;
    const int n0 = blockIdx.x * 1024 + threadIdx.x * 4;
    const float* wseg; const float* bseg; int orel;
    if (o0 < 16)      { wseg = qw; bseg = qb; orel = o0; }
    else if (o0 < 32) { wseg = kw; bseg = kb; orel = o0 - 16; }
    else              { wseg = vw; bseg = vb; orel = o0 - 32; }
    float acc[8][4];
#pragma unroll
    for (int i = 0; i < 8; ++i)
#pragma unroll
        for (int j = 0; j < 4; ++j) acc[i][j] = 0.f;
    for (int c = 0; c < CCH; ++c) {
        float4 f4 = *(const float4*)&feat[(((b << 7) + c) << 12) + n0];
#pragma unroll
        for (int oo = 0; oo < 8; ++oo) {
            float wv = wseg[((orel + oo) << 7) + c];
            acc[oo][0] += wv * f4.x; acc[oo][1] += wv * f4.y;
            acc[oo][2] += wv * f4.z; acc[oo][3] += wv * f4.w;
        }
    }
    if (o0 < 32) {
        unsigned short* dst = (o0 < 16) ? qT : kT;
#pragma unroll
        for (int oo = 0; oo < 8; ++oo) {
            float bias = bseg[orel + oo];
#pragma unroll
            for (int j = 0; j < 4; ++j)
                dst[(((b << 12) + n0 + j) << 4) + orel + oo] = f2bf(acc[oo][j] + bias);
        }
    } else {
#pragma unroll
        for (int oo = 0; oo < 8; ++oo) {
            float bias = bseg[orel + oo];
            ushort4 o;
            o.x = f2bf(acc[oo][0] + bias); o.y = f2bf(acc[oo][1] + bias);
            o.z = f2bf(acc[oo][2] + bias); o.w = f2bf(acc[oo][3] + bias);
            *(ushort4*)&vB[(((b << 7) + orel + oo) << 12) + n0] = o;
        }
    }
}

// ---------------------------------------------------------------------------
// 9) PAM via MFMA 32x32x16 bf16 (both S=K^T.Q and PV), flash-style.
//    Block: (b, m-tile 64, n-half 2048), 4 waves. Wave = c-half x m-half.
//    Per 128-n chunk: wave computes S'[n-sub 32][m 64] (2 MFMA, K=16 exact),
//    tanh -> bf16 pairs -> XOR-swizzled LDS attn[64m][128n]; then 8 k-steps
//    of PV: 2 c-tiles x 1 m-tile, V read from L2 (partner wave hits L1).
//    Epilogue: atomicAdd g*acc into out (2 n-half writers).
// grid(2, 64, 4) = 512 blocks, block 256.
// ---------------------------------------------------------------------------
__global__ __launch_bounds__(256, 2) void pam_mfma_kernel(
        const unsigned short* __restrict__ qT, const unsigned short* __restrict__ kT,
        const unsigned short* __restrict__ vB, const float* __restrict__ gpa,
        float* __restrict__ out) {
    __shared__ unsigned short attn_s[64 * 128];   // [m][n swizzled], 16 KB
    const int b  = blockIdx.z, m0 = blockIdx.y * 64, nh = blockIdx.x;
    const int tid = threadIdx.x;
    const int w = tid >> 6, lane = tid & 63, l31 = lane & 31, hi = lane >> 5;
    const int ch = (w & 1) * 64;        // c-half base
    const int mh = (w >> 1) * 32;       // m-half base

    // loop-invariant Q fragments (B operand of S'): m-tiles 0,1
    short8 bq0 = *(const short8*)&qT[(((b << 12) + m0 + l31) << 4) + hi * 8];
    short8 bq1 = *(const short8*)&qT[(((b << 12) + m0 + 32 + l31) << 4) + hi * 8];

    floatx16 acc0, acc1, zero16;
#pragma unroll
    for (int r = 0; r < 16; ++r) { acc0[r] = 0.f; acc1[r] = 0.f; zero16[r] = 0.f; }

    for (int nc = 0; nc < 16; ++nc) {
        const int na = (nh << 11) + (nc << 7);     // chunk base n
        // ---- S' = K^T Q for this wave's 32-n sub x 64 m ----
        short8 ak = *(const short8*)&kT[(((b << 12) + na + w * 32 + l31) << 4) + hi * 8];
        floatx16 s0 = __builtin_amdgcn_mfma_f32_32x32x16_bf16(ak, bq0, zero16, 0, 0, 0);
        floatx16 s1 = __builtin_amdgcn_mfma_f32_32x32x16_bf16(ak, bq1, zero16, 0, 0, 0);
        // tanh + pack bf16 pairs + swizzled LDS write
#pragma unroll
        for (int j = 0; j < 2; ++j) {
            const floatx16& s = j ? s1 : s0;
            const int m = j * 32 + l31;
            const int mrow = m << 7;
            const int msw  = m & 15;
#pragma unroll
            for (int p = 0; p < 8; ++p) {
                float t0 = fast_tanh(s[2 * p]);
                float t1 = fast_tanh(s[2 * p + 1]);
                unsigned u = (__float_as_uint(t1) & 0xFFFF0000u) |
                             (__float_as_uint(t0) >> 16);
                int n = w * 32 + (p & 1) * 2 + ((p >> 1) << 3) + hi * 4;  // even
                int idx = mrow + ((((n >> 3) ^ msw) << 3) + (n & 7));
                *(unsigned*)&attn_s[idx] = u;
            }
        }
        __syncthreads();
        // ---- PV: acc[c][m] += V[c][kn] * attn[kn][m], 8 k-steps of 16 ----
        const int mread = mh + l31;
        const int mrow  = mread << 7;
        const int msw   = mread & 15;
#pragma unroll
        for (int ks = 0; ks < 8; ++ks) {
            short8 ba = *(const short8*)&attn_s[mrow + (((ks * 2 + hi) ^ msw) << 3)];
            short8 av0 = *(const short8*)&vB[(((b << 7) + ch + l31) << 12) + na + ks * 16 + hi * 8];
            short8 av1 = *(const short8*)&vB[(((b << 7) + ch + 32 + l31) << 12) + na + ks * 16 + hi * 8];
            acc0 = __builtin_amdgcn_mfma_f32_32x32x16_bf16(av0, ba, acc0, 0, 0, 0);
            acc1 = __builtin_amdgcn_mfma_f32_32x32x16_bf16(av1, ba, acc1, 0, 0, 0);
        }
        __syncthreads();
    }
    const float g = gpa[0];
    const int m = m0 + mh + l31;
#pragma unroll
    for (int r = 0; r < 16; ++r) {
        int crow = (r & 3) + ((r >> 2) << 3) + hi * 4;
        atomicAdd(&out[(((b << 7) + ch + crow) << 12) + m], g * acc0[r]);
        atomicAdd(&out[(((b << 7) + ch + 32 + crow) << 12) + m], g * acc1[r]);
    }
}

// ---------------------------------------------------------------------------
extern "C" void kernel_launch(void* const* d_in, const int* in_sizes, int n_in,
                              void* d_out, int out_size, void* d_ws, size_t ws_size,
                              hipStream_t stream) {
    const float* x      = (const float*)d_in[0];
    const float* conv_w = (const float*)d_in[1];
    const float* bn_g   = (const float*)d_in[2];
    const float* bn_b   = (const float*)d_in[3];
    const float* q_w    = (const float*)d_in[4];
    const float* q_b    = (const float*)d_in[5];
    const float* k_w    = (const float*)d_in[6];
    const float* k_b    = (const float*)d_in[7];
    const float* v_w    = (const float*)d_in[8];
    const float* v_b    = (const float*)d_in[9];
    const float* gca    = (const float*)d_in[10];
    const float* gpa    = (const float*)d_in[11];
    float* out = (float*)d_out;

    float* ws     = (float*)d_ws;
    float* feat   = ws;                         // 2,097,152 f
    float* energy = ws + 2097152;               // 65,536 f
    float* scale  = ws + 2162688;               // 128
    float* shift  = ws + 2162816;               // 128
    unsigned short* Wb = (unsigned short*)(ws + 2162944);  // 294,912 bf16
    unsigned short* qT = (unsigned short*)(ws + 2310400);  // 262,144 bf16
    unsigned short* kT = (unsigned short*)(ws + 2441472);  // 262,144 bf16
    unsigned short* vB = (unsigned short*)(ws + 2572544);  // 2,097,152 bf16

    conv_prep_kernel<<<1152, 256, 0, stream>>>(conv_w, Wb);
    conv_mfma_kernel<<<dim3(2, 64, 4), 256, 0, stream>>>(x, Wb, feat);
    bn_stats_kernel<<<128, 256, 0, stream>>>(feat, bn_g, bn_b, scale, shift);
    bn_apply_kernel<<<2048, 256, 0, stream>>>(feat, scale, shift);
    zero_kernel<<<64, 256, 0, stream>>>(energy);
    cam_energy_kernel<<<dim3(64, 4), 256, 0, stream>>>(feat, energy);
    cam_attn_kernel<<<dim3(128, 4), 128, 0, stream>>>(energy);
    qkv_kernel<<<dim3(4, 20, 4), 256, 0, stream>>>(feat, q_w, q_b, k_w, k_b, v_w, v_b, qT, kT, vB);
    cam_out_kernel<<<dim3(64, 4), 256, 0, stream>>>(feat, energy, gca, out);
    pam_mfma_kernel<<<dim3(2, 64, 4), 256, 0, stream>>>(qT, kT, vB, gpa, out);
}

// Round 4
// 303.764 us; speedup vs baseline: 4.1659x; 1.1333x over previous
//
#include <hip/hip_runtime.h>
#include <math.h>

// Problem constants
#define BATCH 4
#define CIN   256
#define CCH   128      // Cout
#define HW    4096     // 64*64
#define CQK   16

using short8   = __attribute__((ext_vector_type(8))) short;
using floatx4  = __attribute__((ext_vector_type(4))) float;
using floatx16 = __attribute__((ext_vector_type(16))) float;

__device__ __forceinline__ float fast_tanh(float x) {
    // 1 - 2/(e^{2x}+1): saturates correctly for large |x|
    float e = __expf(2.0f * x);
    return 1.0f - __fdividef(2.0f, e + 1.0f);
}

__device__ __forceinline__ unsigned short f2bf(float f) {
    unsigned u = __float_as_uint(f);
    u += 0x7fff + ((u >> 16) & 1);   // RNE
    return (unsigned short)(u >> 16);
}

__device__ __forceinline__ float bf2f(unsigned short u) {
    return __uint_as_float(((unsigned)u) << 16);
}

// C/D row map for mfma_f32_32x32x16: row = (r&3) + 8*(r>>2) + 4*hi, col = lane&31
#define ROWMAP(r, hi) (((r) & 3) + (((r) >> 2) << 3) + ((hi) << 2))

// ---------------------------------------------------------------------------
// 1a) Conv weight prep: w[co][ci][3][3] fp32 -> Wb[co][tap][ci] bf16
// ---------------------------------------------------------------------------
__global__ __launch_bounds__(256) void conv_prep_kernel(
        const float* __restrict__ w, unsigned short* __restrict__ Wb) {
    int o = blockIdx.x * 256 + threadIdx.x;          // o < 294912
    int co = o / 2304;
    int rem = o - co * 2304;
    int tap = rem >> 8;
    int ci  = rem & 255;
    Wb[o] = f2bf(w[co * 2304 + ci * 9 + tap]);
}

// ---------------------------------------------------------------------------
// 1c) QKV weight prep: pack q_w/k_w/v_w -> Wqkv[160][128] bf16 + biasAll[160]
// ---------------------------------------------------------------------------
__global__ __launch_bounds__(256) void qkv_prep_kernel(
        const float* __restrict__ qw, const float* __restrict__ qb,
        const float* __restrict__ kw, const float* __restrict__ kb,
        const float* __restrict__ vw, const float* __restrict__ vb,
        unsigned short* __restrict__ Wqkv, float* __restrict__ biasAll) {
    int idx = blockIdx.x * 256 + threadIdx.x;        // < 20480
    int o = idx >> 7, c = idx & 127;
    float w = (o < 16) ? qw[(o << 7) + c]
            : (o < 32) ? kw[((o - 16) << 7) + c]
                       : vw[((o - 32) << 7) + c];
    Wqkv[idx] = f2bf(w);
    if (idx < 160)
        biasAll[idx] = (idx < 16) ? qb[idx] : (idx < 32) ? kb[idx - 16] : vb[idx - 32];
}

// ---------------------------------------------------------------------------
// 1b) Conv as implicit GEMM, bf16 MFMA 16x16x32. (unchanged)
// ---------------------------------------------------------------------------
__global__ __launch_bounds__(256, 2) void conv_mfma_kernel(
        const float* __restrict__ x, const unsigned short* __restrict__ Wb,
        float* __restrict__ y) {
    __shared__ unsigned short xs[3 * 34 * 256];
    const int tid  = threadIdx.x;
    const int x0   = blockIdx.x * 32;
    const int yrow = blockIdx.y;
    const int b    = blockIdx.z;

    for (int e = tid; e < 768 * 34; e += 256) {
        int p  = e / 34;
        int px = e - p * 34;
        int ky = p >> 8, ci = p & 255;
        int gy = yrow + ky - 1;
        int gx = x0 - 1 + px;
        float v = 0.f;
        if (gy >= 0 && gy < 64 && gx >= 0 && gx < 64)
            v = x[(((b << 8) + ci) << 12) + (gy << 6) + gx];
        int c16s = (ci >> 3) ^ (px & 7);
        xs[(ky * 34 + px) * 256 + (c16s << 3) + (ci & 7)] = f2bf(v);
    }
    __syncthreads();

    const int wv   = tid >> 6;
    const int lane = tid & 63;
    const int l15  = lane & 15;
    const int quad = lane >> 4;

    floatx4 acc[2][2];
#pragma unroll
    for (int i = 0; i < 2; ++i)
#pragma unroll
        for (int j = 0; j < 2; ++j) acc[i][j] = (floatx4){0.f, 0.f, 0.f, 0.f};

    const int coA0 = (wv * 32 + l15) * 9;
    const int coA1 = (wv * 32 + 16 + l15) * 9;

#pragma unroll
    for (int ky = 0; ky < 3; ++ky) {
#pragma unroll
        for (int kx = 0; kx < 3; ++kx) {
            const int tap = ky * 3 + kx;
            const int pxn0 = l15 + kx;
            const int pxn1 = 16 + l15 + kx;
            const int rb0 = (ky * 34 + pxn0) * 256;
            const int rb1 = (ky * 34 + pxn1) * 256;
            const int k0s = pxn0 & 7, k1s = pxn1 & 7;
            for (int cc = 0; cc < 8; ++cc) {
                const int ci0 = cc * 32;
                short8 a0 = *(const short8*)(Wb + (coA0 + tap) * 256 + ci0 + quad * 8);
                short8 a1 = *(const short8*)(Wb + (coA1 + tap) * 256 + ci0 + quad * 8);
                int c16 = (ci0 >> 3) + quad;
                short8 b0 = *(const short8*)&xs[rb0 + ((c16 ^ k0s) << 3)];
                short8 b1 = *(const short8*)&xs[rb1 + ((c16 ^ k1s) << 3)];
                acc[0][0] = __builtin_amdgcn_mfma_f32_16x16x32_bf16(a0, b0, acc[0][0], 0, 0, 0);
                acc[0][1] = __builtin_amdgcn_mfma_f32_16x16x32_bf16(a0, b1, acc[0][1], 0, 0, 0);
                acc[1][0] = __builtin_amdgcn_mfma_f32_16x16x32_bf16(a1, b0, acc[1][0], 0, 0, 0);
                acc[1][1] = __builtin_amdgcn_mfma_f32_16x16x32_bf16(a1, b1, acc[1][1], 0, 0, 0);
            }
        }
    }

#pragma unroll
    for (int ms = 0; ms < 2; ++ms)
#pragma unroll
        for (int ns = 0; ns < 2; ++ns) {
            int px = x0 + ns * 16 + l15;
#pragma unroll
            for (int r = 0; r < 4; ++r) {
                int co = wv * 32 + ms * 16 + quad * 4 + r;
                y[(((b << 7) + co) << 12) + (yrow << 6) + px] = acc[ms][ns][r];
            }
        }
}

// ---------------------------------------------------------------------------
// 2) BN stats per channel -> fused scale/shift. grid(128), block 256
// ---------------------------------------------------------------------------
__global__ __launch_bounds__(256) void bn_stats_kernel(
        const float* __restrict__ y, const float* __restrict__ gamma,
        const float* __restrict__ beta, float* __restrict__ scale,
        float* __restrict__ shift) {
    const int c = blockIdx.x, tid = threadIdx.x;
    float s = 0.f, q = 0.f;
    for (int i = tid; i < BATCH * HW; i += 256) {
        float v = y[((((i >> 12) << 7) + c) << 12) + (i & 4095)];
        s += v; q += v * v;
    }
    for (int off = 32; off; off >>= 1) {
        s += __shfl_down(s, off);
        q += __shfl_down(q, off);
    }
    __shared__ float ls[4], lq[4];
    if ((tid & 63) == 0) { ls[tid >> 6] = s; lq[tid >> 6] = q; }
    __syncthreads();
    if (tid == 0) {
        float S = ls[0] + ls[1] + ls[2] + ls[3];
        float Q = lq[0] + lq[1] + lq[2] + lq[3];
        float mean = S * (1.f / 16384.f);
        float var  = Q * (1.f / 16384.f) - mean * mean;
        float rstd = rsqrtf(var + 1e-5f);
        float sc = gamma[c] * rstd;
        scale[c] = sc;
        shift[c] = beta[c] - mean * sc;
    }
}

// ---------------------------------------------------------------------------
// 3) BN apply + ReLU -> featB bf16 [b][c][n] and fT bf16 [b][n][c].
// grid(2048), block 256, 4 elems/thread
// ---------------------------------------------------------------------------
__global__ __launch_bounds__(256) void bn_apply_kernel(
        const float* __restrict__ y, const float* __restrict__ scale,
        const float* __restrict__ shift, unsigned short* __restrict__ featB,
        unsigned short* __restrict__ fT) {
    int base = (blockIdx.x * 256 + threadIdx.x) * 4;
    int b = base >> 19, c = (base >> 12) & 127, n = base & 4095;
    float sc = scale[c], sh = shift[c];
    float4 v = *(const float4*)&y[base];
    float f0 = fmaxf(fmaf(v.x, sc, sh), 0.f);
    float f1 = fmaxf(fmaf(v.y, sc, sh), 0.f);
    float f2 = fmaxf(fmaf(v.z, sc, sh), 0.f);
    float f3 = fmaxf(fmaf(v.w, sc, sh), 0.f);
    ushort4 o;
    o.x = f2bf(f0); o.y = f2bf(f1); o.z = f2bf(f2); o.w = f2bf(f3);
    *(ushort4*)&featB[base] = o;
    fT[(((b << 12) + n + 0) << 7) + c] = o.x;
    fT[(((b << 12) + n + 1) << 7) + c] = o.y;
    fT[(((b << 12) + n + 2) << 7) + c] = o.z;
    fT[(((b << 12) + n + 3) << 7) + c] = o.w;
}

// 4) zero the CAM energy buffer. grid(64), block 256
__global__ __launch_bounds__(256) void zero_kernel(float* __restrict__ p) {
    int idx = (blockIdx.x * 256 + threadIdx.x) * 4;
    *(float4*)&p[idx] = make_float4(0.f, 0.f, 0.f, 0.f);
}

// ---------------------------------------------------------------------------
// 5) CAM energy via MFMA: E[c][d] = sum_n f[c,n]f[d,n]. Split-K 32 + atomics.
// grid(32, 4), block 256. Wave w -> row-tile w, 4 col-tiles. K=128/block.
// One fragment layout serves both A (rows) and B (cols) roles.
// ---------------------------------------------------------------------------
__global__ __launch_bounds__(256) void cam_energy_mfma_kernel(
        const unsigned short* __restrict__ featB, float* __restrict__ energy) {
    const int b = blockIdx.y, kc = blockIdx.x, tid = threadIdx.x;
    const int wv = tid >> 6, l31 = tid & 31, hi = (tid >> 5) & 1;
    floatx16 acc[4];
#pragma unroll
    for (int t = 0; t < 4; ++t)
#pragma unroll
        for (int r = 0; r < 16; ++r) acc[t][r] = 0.f;

    for (int s = 0; s < 8; ++s) {
        const int k0 = (kc << 7) + (s << 4) + (hi << 3);
        short8 fr = *(const short8*)&featB[(((b << 7) + (wv << 5) + l31) << 12) + k0];
        short8 fc0 = *(const short8*)&featB[(((b << 7) +  0 + l31) << 12) + k0];
        short8 fc1 = *(const short8*)&featB[(((b << 7) + 32 + l31) << 12) + k0];
        short8 fc2 = *(const short8*)&featB[(((b << 7) + 64 + l31) << 12) + k0];
        short8 fc3 = *(const short8*)&featB[(((b << 7) + 96 + l31) << 12) + k0];
        acc[0] = __builtin_amdgcn_mfma_f32_32x32x16_bf16(fr, fc0, acc[0], 0, 0, 0);
        acc[1] = __builtin_amdgcn_mfma_f32_32x32x16_bf16(fr, fc1, acc[1], 0, 0, 0);
        acc[2] = __builtin_amdgcn_mfma_f32_32x32x16_bf16(fr, fc2, acc[2], 0, 0, 0);
        acc[3] = __builtin_amdgcn_mfma_f32_32x32x16_bf16(fr, fc3, acc[3], 0, 0, 0);
    }
#pragma unroll
    for (int t = 0; t < 4; ++t)
#pragma unroll
        for (int r = 0; r < 16; ++r) {
            int c = (wv << 5) + ROWMAP(r, hi);
            int d = (t << 5) + l31;
            atomicAdd(&energy[(b << 14) + (c << 7) + d], acc[t][r]);
        }
}

// 6) CAM attn: attnB = bf16(tanh(rowmax - e)). grid(128, 4), block 128
__global__ __launch_bounds__(128) void cam_attn_kernel(
        const float* __restrict__ energy, unsigned short* __restrict__ attnB) {
    const int b = blockIdx.y, c = blockIdx.x, tid = threadIdx.x;
    float v = energy[(b << 14) + (c << 7) + tid];
    float m = v;
    for (int off = 32; off; off >>= 1) m = fmaxf(m, __shfl_down(m, off));
    __shared__ float mx[2];
    if ((tid & 63) == 0) mx[tid >> 6] = m;
    __syncthreads();
    float M = fmaxf(mx[0], mx[1]);
    attnB[(b << 14) + (c << 7) + tid] = f2bf(fast_tanh(M - v));
}

// ---------------------------------------------------------------------------
// 7) CAM out + base via MFMA: out = 3*feat + g_ca * (attn @ f).
// grid(32 mtiles, 4 b), block 256. Wave: 32 m x 128 c (4 c-tiles). K=128.
// ---------------------------------------------------------------------------
__global__ __launch_bounds__(256) void cam_out_mfma_kernel(
        const unsigned short* __restrict__ attnB, const unsigned short* __restrict__ fT,
        const unsigned short* __restrict__ featB, const float* __restrict__ gca,
        float* __restrict__ out) {
    const int b = blockIdx.y, tid = threadIdx.x;
    const int wv = tid >> 6, l31 = tid & 31, hi = (tid >> 5) & 1;
    const int m0 = (blockIdx.x << 7) + (wv << 5);
    floatx16 acc[4];
#pragma unroll
    for (int t = 0; t < 4; ++t)
#pragma unroll
        for (int r = 0; r < 16; ++r) acc[t][r] = 0.f;

    for (int s = 0; s < 8; ++s) {
        const int k0 = (s << 4) + (hi << 3);
        short8 bf = *(const short8*)&fT[(((b << 12) + m0 + l31) << 7) + k0];
        short8 a0 = *(const short8*)&attnB[(b << 14) + (( 0 + l31) << 7) + k0];
        short8 a1 = *(const short8*)&attnB[(b << 14) + ((32 + l31) << 7) + k0];
        short8 a2 = *(const short8*)&attnB[(b << 14) + ((64 + l31) << 7) + k0];
        short8 a3 = *(const short8*)&attnB[(b << 14) + ((96 + l31) << 7) + k0];
        acc[0] = __builtin_amdgcn_mfma_f32_32x32x16_bf16(a0, bf, acc[0], 0, 0, 0);
        acc[1] = __builtin_amdgcn_mfma_f32_32x32x16_bf16(a1, bf, acc[1], 0, 0, 0);
        acc[2] = __builtin_amdgcn_mfma_f32_32x32x16_bf16(a2, bf, acc[2], 0, 0, 0);
        acc[3] = __builtin_amdgcn_mfma_f32_32x32x16_bf16(a3, bf, acc[3], 0, 0, 0);
    }
    const float g = gca[0];
    const int m = m0 + l31;
#pragma unroll
    for (int t = 0; t < 4; ++t)
#pragma unroll
        for (int r = 0; r < 16; ++r) {
            int c = (t << 5) + ROWMAP(r, hi);
            float fb = bf2f(featB[(((b << 7) + c) << 12) + m]);
            out[(((b << 7) + c) << 12) + m] = 3.f * fb + g * acc[t][r];
        }
}

// ---------------------------------------------------------------------------
// 8) QKV via MFMA: [160 o][4096 n] = Wqkv[160][128] @ f^T. K=128.
// grid(32 ntiles, 4 b), block 256. Wave: 32 n x 160 o (5 tiles).
// Outputs: qT[b][n][16], kT[b][n][16] (scatter, small), vB[b][c][n].
// ---------------------------------------------------------------------------
__global__ __launch_bounds__(256) void qkv_mfma_kernel(
        const unsigned short* __restrict__ Wqkv, const float* __restrict__ biasAll,
        const unsigned short* __restrict__ fT,
        unsigned short* __restrict__ qT, unsigned short* __restrict__ kT,
        unsigned short* __restrict__ vB) {
    const int b = blockIdx.y, tid = threadIdx.x;
    const int wv = tid >> 6, l31 = tid & 31, hi = (tid >> 5) & 1;
    const int n0 = (blockIdx.x << 7) + (wv << 5);
    floatx16 acc[5];
#pragma unroll
    for (int t = 0; t < 5; ++t)
#pragma unroll
        for (int r = 0; r < 16; ++r) acc[t][r] = 0.f;

    for (int s = 0; s < 8; ++s) {
        const int k0 = (s << 4) + (hi << 3);
        short8 bf = *(const short8*)&fT[(((b << 12) + n0 + l31) << 7) + k0];
#pragma unroll
        for (int t = 0; t < 5; ++t) {
            short8 aw = *(const short8*)&Wqkv[(((t << 5) + l31) << 7) + k0];
            acc[t] = __builtin_amdgcn_mfma_f32_32x32x16_bf16(aw, bf, acc[t], 0, 0, 0);
        }
    }
    const int n = n0 + l31;
#pragma unroll
    for (int t = 0; t < 5; ++t)
#pragma unroll
        for (int r = 0; r < 16; ++r) {
            int o = (t << 5) + ROWMAP(r, hi);
            float val = acc[t][r] + biasAll[o];
            if (t == 0) {
                if (o < 16) qT[(((b << 12) + n) << 4) + o] = f2bf(val);
                else        kT[(((b << 12) + n) << 4) + o - 16] = f2bf(val);
            } else if (t >= 1 && o >= 32) {
                vB[(((b << 7) + o - 32) << 12) + n] = f2bf(val);
            }
        }
}

// ---------------------------------------------------------------------------
// 9) PAM via MFMA 32x32x16 bf16, flash-style. grid(4 n-quarters, 64, 4),
// block 256, 4 blocks/CU. Per 128-n chunk: S' -> tanh -> bf16 swizzled LDS
// -> PV. Epilogue: atomicAdd (4 n-quarter writers).
// ---------------------------------------------------------------------------
__global__ __launch_bounds__(256, 4) void pam_mfma_kernel(
        const unsigned short* __restrict__ qT, const unsigned short* __restrict__ kT,
        const unsigned short* __restrict__ vB, const float* __restrict__ gpa,
        float* __restrict__ out) {
    __shared__ unsigned short attn_s[64 * 128];   // [m][n swizzled], 16 KB
    const int b  = blockIdx.z, m0 = blockIdx.y * 64, nh = blockIdx.x;
    const int tid = threadIdx.x;
    const int w = tid >> 6, lane = tid & 63, l31 = lane & 31, hi = lane >> 5;
    const int ch = (w & 1) * 64;        // c-half base
    const int mh = (w >> 1) * 32;       // m-half base

    short8 bq0 = *(const short8*)&qT[(((b << 12) + m0 + l31) << 4) + hi * 8];
    short8 bq1 = *(const short8*)&qT[(((b << 12) + m0 + 32 + l31) << 4) + hi * 8];

    floatx16 acc0, acc1, zero16;
#pragma unroll
    for (int r = 0; r < 16; ++r) { acc0[r] = 0.f; acc1[r] = 0.f; zero16[r] = 0.f; }

    for (int nc = 0; nc < 8; ++nc) {
        const int na = (nh << 10) + (nc << 7);     // chunk base n
        short8 ak = *(const short8*)&kT[(((b << 12) + na + w * 32 + l31) << 4) + hi * 8];
        floatx16 s0 = __builtin_amdgcn_mfma_f32_32x32x16_bf16(ak, bq0, zero16, 0, 0, 0);
        floatx16 s1 = __builtin_amdgcn_mfma_f32_32x32x16_bf16(ak, bq1, zero16, 0, 0, 0);
#pragma unroll
        for (int j = 0; j < 2; ++j) {
            const floatx16& s = j ? s1 : s0;
            const int m = j * 32 + l31;
            const int mrow = m << 7;
            const int msw  = m & 15;
#pragma unroll
            for (int p = 0; p < 8; ++p) {
                float t0 = fast_tanh(s[2 * p]);
                float t1 = fast_tanh(s[2 * p + 1]);
                unsigned u = (__float_as_uint(t1) & 0xFFFF0000u) |
                             (__float_as_uint(t0) >> 16);
                int n = w * 32 + (p & 1) * 2 + ((p >> 1) << 3) + hi * 4;  // even
                int idx = mrow + ((((n >> 3) ^ msw) << 3) + (n & 7));
                *(unsigned*)&attn_s[idx] = u;
            }
        }
        __syncthreads();
        const int mread = mh + l31;
        const int mrow  = mread << 7;
        const int msw   = mread & 15;
#pragma unroll
        for (int ks = 0; ks < 8; ++ks) {
            short8 ba = *(const short8*)&attn_s[mrow + (((ks * 2 + hi) ^ msw) << 3)];
            short8 av0 = *(const short8*)&vB[(((b << 7) + ch + l31) << 12) + na + ks * 16 + hi * 8];
            short8 av1 = *(const short8*)&vB[(((b << 7) + ch + 32 + l31) << 12) + na + ks * 16 + hi * 8];
            acc0 = __builtin_amdgcn_mfma_f32_32x32x16_bf16(av0, ba, acc0, 0, 0, 0);
            acc1 = __builtin_amdgcn_mfma_f32_32x32x16_bf16(av1, ba, acc1, 0, 0, 0);
        }
        __syncthreads();
    }
    const float g = gpa[0];
    const int m = m0 + mh + l31;
#pragma unroll
    for (int r = 0; r < 16; ++r) {
        int crow = ROWMAP(r, hi);
        atomicAdd(&out[(((b << 7) + ch + crow) << 12) + m], g * acc0[r]);
        atomicAdd(&out[(((b << 7) + ch + 32 + crow) << 12) + m], g * acc1[r]);
    }
}

// ---------------------------------------------------------------------------
extern "C" void kernel_launch(void* const* d_in, const int* in_sizes, int n_in,
                              void* d_out, int out_size, void* d_ws, size_t ws_size,
                              hipStream_t stream) {
    const float* x      = (const float*)d_in[0];
    const float* conv_w = (const float*)d_in[1];
    const float* bn_g   = (const float*)d_in[2];
    const float* bn_b   = (const float*)d_in[3];
    const float* q_w    = (const float*)d_in[4];
    const float* q_b    = (const float*)d_in[5];
    const float* k_w    = (const float*)d_in[6];
    const float* k_b    = (const float*)d_in[7];
    const float* v_w    = (const float*)d_in[8];
    const float* v_b    = (const float*)d_in[9];
    const float* gca    = (const float*)d_in[10];
    const float* gpa    = (const float*)d_in[11];
    float* out = (float*)d_out;

    float* ws     = (float*)d_ws;
    float* convY  = ws;                          // [0, 2097152) fp32 conv out
    float* energy = ws + 2097152;                // 65,536 f
    float* scale  = ws + 2162688;                // 128
    float* shift  = ws + 2162816;                // 128
    float* biasAll= ws + 2162944;                // 160
    unsigned short* Wb    = (unsigned short*)(ws + 2163104);  // 294,912 bf16 (147,456 f)
    unsigned short* qT    = (unsigned short*)(ws + 2310560);  // 262,144 bf16 (131,072 f)
    unsigned short* kT    = (unsigned short*)(ws + 2441632);  // 262,144 bf16
    unsigned short* vB    = (unsigned short*)(ws + 2572704);  // 2,097,152 bf16 (1,048,576 f)
    unsigned short* featB = (unsigned short*)(ws + 3621280);  // 2,097,152 bf16
    unsigned short* fT    = (unsigned short*)(ws + 4669856);  // 2,097,152 bf16
    unsigned short* Wqkv  = (unsigned short*)(ws + 5718432);  // 20,480 bf16
    unsigned short* attnB = (unsigned short*)(ws + 5728672);  // 65,536 bf16

    conv_prep_kernel<<<1152, 256, 0, stream>>>(conv_w, Wb);
    qkv_prep_kernel<<<80, 256, 0, stream>>>(q_w, q_b, k_w, k_b, v_w, v_b, Wqkv, biasAll);
    conv_mfma_kernel<<<dim3(2, 64, 4), 256, 0, stream>>>(x, Wb, convY);
    bn_stats_kernel<<<128, 256, 0, stream>>>(convY, bn_g, bn_b, scale, shift);
    bn_apply_kernel<<<2048, 256, 0, stream>>>(convY, scale, shift, featB, fT);
    zero_kernel<<<64, 256, 0, stream>>>(energy);
    cam_energy_mfma_kernel<<<dim3(32, 4), 256, 0, stream>>>(featB, energy);
    cam_attn_kernel<<<dim3(128, 4), 128, 0, stream>>>(energy, attnB);
    qkv_mfma_kernel<<<dim3(32, 4), 256, 0, stream>>>(Wqkv, biasAll, fT, qT, kT, vB);
    cam_out_mfma_kernel<<<dim3(32, 4), 256, 0, stream>>>(attnB, fT, featB, gca, out);
    pam_mfma_kernel<<<dim3(4, 64, 4), 256, 0, stream>>>(qT, kT, vB, gpa, out);
}

// Round 5
// 282.606 us; speedup vs baseline: 4.4777x; 1.0749x over previous
//
#include <hip/hip_runtime.h>
#include <math.h>

// Problem constants
#define BATCH 4
#define CIN   256
#define CCH   128      // Cout
#define HW    4096     // 64*64
#define CQK   16

using short8   = __attribute__((ext_vector_type(8))) short;
using floatx4  = __attribute__((ext_vector_type(4))) float;
using floatx16 = __attribute__((ext_vector_type(16))) float;

__device__ __forceinline__ float fast_tanh(float x) {
    float e = __expf(2.0f * x);
    return 1.0f - __fdividef(2.0f, e + 1.0f);
}

__device__ __forceinline__ unsigned short f2bf(float f) {
    unsigned u = __float_as_uint(f);
    u += 0x7fff + ((u >> 16) & 1);   // RNE
    return (unsigned short)(u >> 16);
}

__device__ __forceinline__ float bf2f(unsigned short u) {
    return __uint_as_float(((unsigned)u) << 16);
}

// C/D row map for mfma_f32_32x32x16: row = (r&3) + 8*(r>>2) + 4*hi, col = lane&31
#define ROWMAP(r, hi) (((r) & 3) + (((r) >> 2) << 3) + ((hi) << 2))

#define XTP_ROW   (66 * 256)          // shorts per padded row
#define XTP_BATCH (66 * 66 * 256)     // shorts per batch

// ---------------------------------------------------------------------------
// 0) zero xTp (padded transposed input, incl. halo). grid(2178), block 256
// ---------------------------------------------------------------------------
__global__ __launch_bounds__(256) void zero_xtp_kernel(float* __restrict__ p) {
    int idx = (blockIdx.x * 256 + threadIdx.x) * 4;   // < 2,230,272 floats
    *(float4*)&p[idx] = make_float4(0.f, 0.f, 0.f, 0.f);
}

// ---------------------------------------------------------------------------
// 0b) transpose x [b][ci][y][x] fp32 -> xTp [b][y+1][x+1][ci] bf16 (interior)
// grid(4 ci-tiles, 64 y, 4 b), block 256; LDS 64x72 tile
// ---------------------------------------------------------------------------
__global__ __launch_bounds__(256) void xt_prep_kernel(
        const float* __restrict__ x, unsigned short* __restrict__ xTp) {
    __shared__ unsigned short lds[64][72];
    const int tid = threadIdx.x;
    const int ci0 = blockIdx.x * 64, yr = blockIdx.y, b = blockIdx.z;
    const int cir = tid >> 2, xc = tid & 3;
    const float* xp = x + (((b << 8) + ci0 + cir) << 12) + (yr << 6) + xc * 16;
#pragma unroll
    for (int j = 0; j < 4; ++j) {
        float4 v = *(const float4*)(xp + j * 4);
        int xi = xc * 16 + j * 4;
        lds[xi + 0][cir] = f2bf(v.x);
        lds[xi + 1][cir] = f2bf(v.y);
        lds[xi + 2][cir] = f2bf(v.z);
        lds[xi + 3][cir] = f2bf(v.w);
    }
    __syncthreads();
    const int xr = tid >> 2, part = tid & 3;
    unsigned short* dst = xTp + b * XTP_BATCH + (yr + 1) * XTP_ROW +
                          (xr + 1) * 256 + ci0 + part * 16;
    *(short8*)(dst + 0) = *(const short8*)&lds[xr][part * 16 + 0];
    *(short8*)(dst + 8) = *(const short8*)&lds[xr][part * 16 + 8];
}

// ---------------------------------------------------------------------------
// 1a) Conv weight prep: w[co][ci][3][3] fp32 -> Wb2[tap][cc][co][s] bf16
//     (s = ci within 32-chunk; A-fragments become lane-contiguous)
// ---------------------------------------------------------------------------
__global__ __launch_bounds__(256) void conv_prep_kernel(
        const float* __restrict__ w, unsigned short* __restrict__ Wb2) {
    int o = blockIdx.x * 256 + threadIdx.x;          // o < 294912
    int s   = o & 31;
    int co  = (o >> 5) & 127;
    int cc  = (o >> 12) & 7;
    int tap = o >> 15;
    int ci  = (cc << 5) + s;
    Wb2[o] = f2bf(w[co * 2304 + ci * 9 + tap]);
}

// ---------------------------------------------------------------------------
// 1c) QKV weight prep: pack q_w/k_w/v_w -> Wqkv[160][128] bf16 + biasAll[160]
// ---------------------------------------------------------------------------
__global__ __launch_bounds__(256) void qkv_prep_kernel(
        const float* __restrict__ qw, const float* __restrict__ qb,
        const float* __restrict__ kw, const float* __restrict__ kb,
        const float* __restrict__ vw, const float* __restrict__ vb,
        unsigned short* __restrict__ Wqkv, float* __restrict__ biasAll) {
    int idx = blockIdx.x * 256 + threadIdx.x;        // < 20480
    int o = idx >> 7, c = idx & 127;
    float w = (o < 16) ? qw[(o << 7) + c]
            : (o < 32) ? kw[((o - 16) << 7) + c]
                       : vw[((o - 32) << 7) + c];
    Wqkv[idx] = f2bf(w);
    if (idx < 160)
        biasAll[idx] = (idx < 16) ? qb[idx] : (idx < 32) ? kb[idx - 16] : vb[idx - 32];
}

// ---------------------------------------------------------------------------
// 1b) Conv implicit GEMM, bf16 MFMA 16x16x32 — LDS-free, barrier-free.
//     Wave = 32co x 32px; block = 4 waves (co-groups) at one (x-half, y, b).
//     A-frags from Wb2 (L2, coalesced), B-frags from xTp (L2, coalesced).
// grid(2, 64, 4) = 512 blocks, block 256.
// ---------------------------------------------------------------------------
__global__ __launch_bounds__(256) void conv_mfma_kernel(
        const unsigned short* __restrict__ xTp, const unsigned short* __restrict__ Wb2,
        float* __restrict__ y) {
    const int tid = threadIdx.x;
    const int w = tid >> 6, lane = tid & 63, l15 = lane & 15, quad = lane >> 4;
    const int x0 = blockIdx.x * 32, yr = blockIdx.y, b = blockIdx.z;

    floatx4 acc[2][2];
#pragma unroll
    for (int i = 0; i < 2; ++i)
#pragma unroll
        for (int j = 0; j < 2; ++j) acc[i][j] = (floatx4){0.f, 0.f, 0.f, 0.f};

    const unsigned short* xb = xTp + b * XTP_BATCH + yr * XTP_ROW;
    const int aco0 = (w << 5) + l15;      // A co row (frag 0); +16 for frag 1

#pragma unroll
    for (int ky = 0; ky < 3; ++ky) {
#pragma unroll
        for (int kx = 0; kx < 3; ++kx) {
            const unsigned short* arow = Wb2 + ((ky * 3 + kx) << 15);
            const unsigned short* brow = xb + ky * XTP_ROW + (x0 + kx) * 256;
#pragma unroll
            for (int cc = 0; cc < 8; ++cc) {
                short8 a0 = *(const short8*)(arow + (((cc << 7) + aco0) << 5) + quad * 8);
                short8 a1 = *(const short8*)(arow + (((cc << 7) + aco0 + 16) << 5) + quad * 8);
                short8 b0 = *(const short8*)(brow + (l15 << 8) + (cc << 5) + quad * 8);
                short8 b1 = *(const short8*)(brow + ((16 + l15) << 8) + (cc << 5) + quad * 8);
                acc[0][0] = __builtin_amdgcn_mfma_f32_16x16x32_bf16(a0, b0, acc[0][0], 0, 0, 0);
                acc[0][1] = __builtin_amdgcn_mfma_f32_16x16x32_bf16(a0, b1, acc[0][1], 0, 0, 0);
                acc[1][0] = __builtin_amdgcn_mfma_f32_16x16x32_bf16(a1, b0, acc[1][0], 0, 0, 0);
                acc[1][1] = __builtin_amdgcn_mfma_f32_16x16x32_bf16(a1, b1, acc[1][1], 0, 0, 0);
            }
        }
    }

#pragma unroll
    for (int ms = 0; ms < 2; ++ms)
#pragma unroll
        for (int ns = 0; ns < 2; ++ns) {
            int px = x0 + ns * 16 + l15;
#pragma unroll
            for (int r = 0; r < 4; ++r) {
                int co = (w << 5) + ms * 16 + quad * 4 + r;
                y[(((b << 7) + co) << 12) + (yr << 6) + px] = acc[ms][ns][r];
            }
        }
}

// ---------------------------------------------------------------------------
// 2) BN stats per channel -> fused scale/shift. grid(128), block 256
// ---------------------------------------------------------------------------
__global__ __launch_bounds__(256) void bn_stats_kernel(
        const float* __restrict__ y, const float* __restrict__ gamma,
        const float* __restrict__ beta, float* __restrict__ scale,
        float* __restrict__ shift) {
    const int c = blockIdx.x, tid = threadIdx.x;
    float s = 0.f, q = 0.f;
    for (int i = tid; i < BATCH * HW; i += 256) {
        float v = y[((((i >> 12) << 7) + c) << 12) + (i & 4095)];
        s += v; q += v * v;
    }
    for (int off = 32; off; off >>= 1) {
        s += __shfl_down(s, off);
        q += __shfl_down(q, off);
    }
    __shared__ float ls[4], lq[4];
    if ((tid & 63) == 0) { ls[tid >> 6] = s; lq[tid >> 6] = q; }
    __syncthreads();
    if (tid == 0) {
        float S = ls[0] + ls[1] + ls[2] + ls[3];
        float Q = lq[0] + lq[1] + lq[2] + lq[3];
        float mean = S * (1.f / 16384.f);
        float var  = Q * (1.f / 16384.f) - mean * mean;
        float rstd = rsqrtf(var + 1e-5f);
        float sc = gamma[c] * rstd;
        scale[c] = sc;
        shift[c] = beta[c] - mean * sc;
    }
}

// ---------------------------------------------------------------------------
// 3) BN apply + ReLU -> featB bf16 [b][c][n] and fT bf16 [b][n][c].
// ---------------------------------------------------------------------------
__global__ __launch_bounds__(256) void bn_apply_kernel(
        const float* __restrict__ y, const float* __restrict__ scale,
        const float* __restrict__ shift, unsigned short* __restrict__ featB,
        unsigned short* __restrict__ fT) {
    int base = (blockIdx.x * 256 + threadIdx.x) * 4;
    int b = base >> 19, c = (base >> 12) & 127, n = base & 4095;
    float sc = scale[c], sh = shift[c];
    float4 v = *(const float4*)&y[base];
    float f0 = fmaxf(fmaf(v.x, sc, sh), 0.f);
    float f1 = fmaxf(fmaf(v.y, sc, sh), 0.f);
    float f2 = fmaxf(fmaf(v.z, sc, sh), 0.f);
    float f3 = fmaxf(fmaf(v.w, sc, sh), 0.f);
    ushort4 o;
    o.x = f2bf(f0); o.y = f2bf(f1); o.z = f2bf(f2); o.w = f2bf(f3);
    *(ushort4*)&featB[base] = o;
    fT[(((b << 12) + n + 0) << 7) + c] = o.x;
    fT[(((b << 12) + n + 1) << 7) + c] = o.y;
    fT[(((b << 12) + n + 2) << 7) + c] = o.z;
    fT[(((b << 12) + n + 3) << 7) + c] = o.w;
}

// ---------------------------------------------------------------------------
// 5) CAM energy via MFMA, split-K 32, PLAIN partial stores (no atomics).
// grid(32, 4), block 256 -> ep[kc][b][c][d] fp32
// ---------------------------------------------------------------------------
__global__ __launch_bounds__(256) void cam_energy_mfma_kernel(
        const unsigned short* __restrict__ featB, float* __restrict__ ep) {
    const int b = blockIdx.y, kc = blockIdx.x, tid = threadIdx.x;
    const int wv = tid >> 6, l31 = tid & 31, hi = (tid >> 5) & 1;
    floatx16 acc[4];
#pragma unroll
    for (int t = 0; t < 4; ++t)
#pragma unroll
        for (int r = 0; r < 16; ++r) acc[t][r] = 0.f;

    for (int s = 0; s < 8; ++s) {
        const int k0 = (kc << 7) + (s << 4) + (hi << 3);
        short8 fr = *(const short8*)&featB[(((b << 7) + (wv << 5) + l31) << 12) + k0];
        short8 fc0 = *(const short8*)&featB[(((b << 7) +  0 + l31) << 12) + k0];
        short8 fc1 = *(const short8*)&featB[(((b << 7) + 32 + l31) << 12) + k0];
        short8 fc2 = *(const short8*)&featB[(((b << 7) + 64 + l31) << 12) + k0];
        short8 fc3 = *(const short8*)&featB[(((b << 7) + 96 + l31) << 12) + k0];
        acc[0] = __builtin_amdgcn_mfma_f32_32x32x16_bf16(fr, fc0, acc[0], 0, 0, 0);
        acc[1] = __builtin_amdgcn_mfma_f32_32x32x16_bf16(fr, fc1, acc[1], 0, 0, 0);
        acc[2] = __builtin_amdgcn_mfma_f32_32x32x16_bf16(fr, fc2, acc[2], 0, 0, 0);
        acc[3] = __builtin_amdgcn_mfma_f32_32x32x16_bf16(fr, fc3, acc[3], 0, 0, 0);
    }
#pragma unroll
    for (int t = 0; t < 4; ++t)
#pragma unroll
        for (int r = 0; r < 16; ++r) {
            int c = (wv << 5) + ROWMAP(r, hi);
            int d = (t << 5) + l31;
            ep[(((kc << 2) + b) << 14) + (c << 7) + d] = acc[t][r];
        }
}

// 6) CAM attn: sum 32 partials, attnB = bf16(tanh(rowmax - e)). grid(128,4)
__global__ __launch_bounds__(128) void cam_attn_kernel(
        const float* __restrict__ ep, unsigned short* __restrict__ attnB) {
    const int b = blockIdx.y, c = blockIdx.x, tid = threadIdx.x;
    float v = 0.f;
#pragma unroll
    for (int s = 0; s < 32; ++s)
        v += ep[(((s << 2) + b) << 14) + (c << 7) + tid];
    float m = v;
    for (int off = 32; off; off >>= 1) m = fmaxf(m, __shfl_down(m, off));
    __shared__ float mx[2];
    if ((tid & 63) == 0) mx[tid >> 6] = m;
    __syncthreads();
    float M = fmaxf(mx[0], mx[1]);
    attnB[(b << 14) + (c << 7) + tid] = f2bf(fast_tanh(M - v));
}

// ---------------------------------------------------------------------------
// 8) QKV via MFMA. grid(32 ntiles, 4 b), block 256.
// ---------------------------------------------------------------------------
__global__ __launch_bounds__(256) void qkv_mfma_kernel(
        const unsigned short* __restrict__ Wqkv, const float* __restrict__ biasAll,
        const unsigned short* __restrict__ fT,
        unsigned short* __restrict__ qT, unsigned short* __restrict__ kT,
        unsigned short* __restrict__ vB) {
    const int b = blockIdx.y, tid = threadIdx.x;
    const int wv = tid >> 6, l31 = tid & 31, hi = (tid >> 5) & 1;
    const int n0 = (blockIdx.x << 7) + (wv << 5);
    floatx16 acc[5];
#pragma unroll
    for (int t = 0; t < 5; ++t)
#pragma unroll
        for (int r = 0; r < 16; ++r) acc[t][r] = 0.f;

    for (int s = 0; s < 8; ++s) {
        const int k0 = (s << 4) + (hi << 3);
        short8 bf = *(const short8*)&fT[(((b << 12) + n0 + l31) << 7) + k0];
#pragma unroll
        for (int t = 0; t < 5; ++t) {
            short8 aw = *(const short8*)&Wqkv[(((t << 5) + l31) << 7) + k0];
            acc[t] = __builtin_amdgcn_mfma_f32_32x32x16_bf16(aw, bf, acc[t], 0, 0, 0);
        }
    }
    const int n = n0 + l31;
#pragma unroll
    for (int t = 0; t < 5; ++t)
#pragma unroll
        for (int r = 0; r < 16; ++r) {
            int o = (t << 5) + ROWMAP(r, hi);
            float val = acc[t][r] + biasAll[o];
            if (t == 0) {
                if (o < 16) qT[(((b << 12) + n) << 4) + o] = f2bf(val);
                else        kT[(((b << 12) + n) << 4) + o - 16] = f2bf(val);
            } else if (o >= 32) {
                vB[(((b << 7) + o - 32) << 12) + n] = f2bf(val);
            }
        }
}

// ---------------------------------------------------------------------------
// 9) PAM via MFMA 32x32x16 bf16, flash-style. grid(4 n-quarters, 64, 4),
// 4 blocks/CU. Partial results -> pamP[nh] bf16, plain coalesced stores.
// ---------------------------------------------------------------------------
__global__ __launch_bounds__(256, 4) void pam_mfma_kernel(
        const unsigned short* __restrict__ qT, const unsigned short* __restrict__ kT,
        const unsigned short* __restrict__ vB, unsigned short* __restrict__ pamP) {
    __shared__ unsigned short attn_s[64 * 128];   // [m][n swizzled], 16 KB
    const int b  = blockIdx.z, m0 = blockIdx.y * 64, nh = blockIdx.x;
    const int tid = threadIdx.x;
    const int w = tid >> 6, lane = tid & 63, l31 = lane & 31, hi = lane >> 5;
    const int ch = (w & 1) * 64;        // c-half base
    const int mh = (w >> 1) * 32;       // m-half base

    short8 bq0 = *(const short8*)&qT[(((b << 12) + m0 + l31) << 4) + hi * 8];
    short8 bq1 = *(const short8*)&qT[(((b << 12) + m0 + 32 + l31) << 4) + hi * 8];

    floatx16 acc0, acc1, zero16;
#pragma unroll
    for (int r = 0; r < 16; ++r) { acc0[r] = 0.f; acc1[r] = 0.f; zero16[r] = 0.f; }

    short8 ak = *(const short8*)&kT[(((b << 12) + (nh << 10) + w * 32 + l31) << 4) + hi * 8];

    for (int nc = 0; nc < 8; ++nc) {
        const int na = (nh << 10) + (nc << 7);     // chunk base n
        floatx16 s0 = __builtin_amdgcn_mfma_f32_32x32x16_bf16(ak, bq0, zero16, 0, 0, 0);
        floatx16 s1 = __builtin_amdgcn_mfma_f32_32x32x16_bf16(ak, bq1, zero16, 0, 0, 0);
        // prefetch next chunk's K fragment under the tanh phase
        short8 ak_n = ak;
        if (nc < 7)
            ak_n = *(const short8*)&kT[(((b << 12) + na + 128 + w * 32 + l31) << 4) + hi * 8];
#pragma unroll
        for (int j = 0; j < 2; ++j) {
            const floatx16& s = j ? s1 : s0;
            const int m = j * 32 + l31;
            const int mrow = m << 7;
            const int msw  = m & 15;
#pragma unroll
            for (int p = 0; p < 8; ++p) {
                float t0 = fast_tanh(s[2 * p]);
                float t1 = fast_tanh(s[2 * p + 1]);
                unsigned u = (__float_as_uint(t1) & 0xFFFF0000u) |
                             (__float_as_uint(t0) >> 16);
                int n = w * 32 + (p & 1) * 2 + ((p >> 1) << 3) + hi * 4;  // even
                int idx = mrow + ((((n >> 3) ^ msw) << 3) + (n & 7));
                *(unsigned*)&attn_s[idx] = u;
            }
        }
        __syncthreads();
        const int mread = mh + l31;
        const int mrow  = mread << 7;
        const int msw   = mread & 15;
#pragma unroll
        for (int ks = 0; ks < 8; ++ks) {
            short8 ba = *(const short8*)&attn_s[mrow + (((ks * 2 + hi) ^ msw) << 3)];
            short8 av0 = *(const short8*)&vB[(((b << 7) + ch + l31) << 12) + na + ks * 16 + hi * 8];
            short8 av1 = *(const short8*)&vB[(((b << 7) + ch + 32 + l31) << 12) + na + ks * 16 + hi * 8];
            acc0 = __builtin_amdgcn_mfma_f32_32x32x16_bf16(av0, ba, acc0, 0, 0, 0);
            acc1 = __builtin_amdgcn_mfma_f32_32x32x16_bf16(av1, ba, acc1, 0, 0, 0);
        }
        __syncthreads();
        ak = ak_n;
    }
    const int m = m0 + mh + l31;
    const int pbase = (((nh << 2) + b) << 19) + m;
#pragma unroll
    for (int r = 0; r < 16; ++r) {
        int crow = ROWMAP(r, hi);
        pamP[pbase + ((ch + crow) << 12)]      = f2bf(acc0[r]);
        pamP[pbase + ((ch + 32 + crow) << 12)] = f2bf(acc1[r]);
    }
}

// ---------------------------------------------------------------------------
// 7) Combine: out = 3*feat + g_ca*(attn @ f) + g_pa*(sum pamP). grid(32,4)
// ---------------------------------------------------------------------------
__global__ __launch_bounds__(256) void combine_kernel(
        const unsigned short* __restrict__ attnB, const unsigned short* __restrict__ fT,
        const unsigned short* __restrict__ featB, const unsigned short* __restrict__ pamP,
        const float* __restrict__ gca, const float* __restrict__ gpa,
        float* __restrict__ out) {
    const int b = blockIdx.y, tid = threadIdx.x;
    const int wv = tid >> 6, l31 = tid & 31, hi = (tid >> 5) & 1;
    const int m0 = (blockIdx.x << 7) + (wv << 5);
    floatx16 acc[4];
#pragma unroll
    for (int t = 0; t < 4; ++t)
#pragma unroll
        for (int r = 0; r < 16; ++r) acc[t][r] = 0.f;

    for (int s = 0; s < 8; ++s) {
        const int k0 = (s << 4) + (hi << 3);
        short8 bf = *(const short8*)&fT[(((b << 12) + m0 + l31) << 7) + k0];
        short8 a0 = *(const short8*)&attnB[(b << 14) + (( 0 + l31) << 7) + k0];
        short8 a1 = *(const short8*)&attnB[(b << 14) + ((32 + l31) << 7) + k0];
        short8 a2 = *(const short8*)&attnB[(b << 14) + ((64 + l31) << 7) + k0];
        short8 a3 = *(const short8*)&attnB[(b << 14) + ((96 + l31) << 7) + k0];
        acc[0] = __builtin_amdgcn_mfma_f32_32x32x16_bf16(a0, bf, acc[0], 0, 0, 0);
        acc[1] = __builtin_amdgcn_mfma_f32_32x32x16_bf16(a1, bf, acc[1], 0, 0, 0);
        acc[2] = __builtin_amdgcn_mfma_f32_32x32x16_bf16(a2, bf, acc[2], 0, 0, 0);
        acc[3] = __builtin_amdgcn_mfma_f32_32x32x16_bf16(a3, bf, acc[3], 0, 0, 0);
    }
    const float gc = gca[0], gp = gpa[0];
    const int m = m0 + l31;
#pragma unroll
    for (int t = 0; t < 4; ++t)
#pragma unroll
        for (int r = 0; r < 16; ++r) {
            int c = (t << 5) + ROWMAP(r, hi);
            int ci = (c << 12) + m;
            float p = bf2f(pamP[((0 * 4 + b) << 19) + ci]) +
                      bf2f(pamP[((1 * 4 + b) << 19) + ci]) +
                      bf2f(pamP[((2 * 4 + b) << 19) + ci]) +
                      bf2f(pamP[((3 * 4 + b) << 19) + ci]);
            float fb = bf2f(featB[(((b << 7) + c) << 12) + m]);
            out[(((b << 7) + c) << 12) + m] = 3.f * fb + gc * acc[t][r] + gp * p;
        }
}

// ---------------------------------------------------------------------------
extern "C" void kernel_launch(void* const* d_in, const int* in_sizes, int n_in,
                              void* d_out, int out_size, void* d_ws, size_t ws_size,
                              hipStream_t stream) {
    const float* x      = (const float*)d_in[0];
    const float* conv_w = (const float*)d_in[1];
    const float* bn_g   = (const float*)d_in[2];
    const float* bn_b   = (const float*)d_in[3];
    const float* q_w    = (const float*)d_in[4];
    const float* q_b    = (const float*)d_in[5];
    const float* k_w    = (const float*)d_in[6];
    const float* k_b    = (const float*)d_in[7];
    const float* v_w    = (const float*)d_in[8];
    const float* v_b    = (const float*)d_in[9];
    const float* gca    = (const float*)d_in[10];
    const float* gpa    = (const float*)d_in[11];
    float* out = (float*)d_out;

    float* ws = (float*)d_ws;
    // layout (floats):
    float* convY  = ws;                                     // [0, 2,097,152)
    unsigned short* xTp = (unsigned short*)(ws + 2097152);  // 4,460,544 sh -> [2,097,152, 4,327,424)
    float* ep     = ws + 4327424;                           // 2,097,152 f
    float* scale  = ws + 6424576;                           // 128
    float* shift  = ws + 6424704;                           // 128
    float* biasAll= ws + 6424832;                           // 256 (pad)
    unsigned short* Wb2   = (unsigned short*)(ws + 6425088); // 294,912 sh
    unsigned short* Wqkv  = (unsigned short*)(ws + 6572544); // 20,480 sh
    unsigned short* attnB = (unsigned short*)(ws + 6582784); // 65,536 sh
    unsigned short* qT    = (unsigned short*)(ws + 6615552); // 262,144 sh
    unsigned short* kT    = (unsigned short*)(ws + 6746624); // 262,144 sh
    unsigned short* vB    = (unsigned short*)(ws + 6877696); // 2,097,152 sh
    unsigned short* featB = (unsigned short*)(ws + 7926272); // 2,097,152 sh
    unsigned short* fT    = (unsigned short*)(ws + 8974848); // 2,097,152 sh
    // pamP bf16[4][4][128][4096] = 8,388,608 sh, ALIASES convY+xTp (both dead
    // by the time pam_mfma runs; fully overwritten before combine reads it)
    unsigned short* pamP  = (unsigned short*)ws;

    zero_xtp_kernel<<<2178, 256, 0, stream>>>((float*)xTp);
    xt_prep_kernel<<<dim3(4, 64, 4), 256, 0, stream>>>(x, xTp);
    conv_prep_kernel<<<1152, 256, 0, stream>>>(conv_w, Wb2);
    qkv_prep_kernel<<<80, 256, 0, stream>>>(q_w, q_b, k_w, k_b, v_w, v_b, Wqkv, biasAll);
    conv_mfma_kernel<<<dim3(2, 64, 4), 256, 0, stream>>>(xTp, Wb2, convY);
    bn_stats_kernel<<<128, 256, 0, stream>>>(convY, bn_g, bn_b, scale, shift);
    bn_apply_kernel<<<2048, 256, 0, stream>>>(convY, scale, shift, featB, fT);
    cam_energy_mfma_kernel<<<dim3(32, 4), 256, 0, stream>>>(featB, ep);
    cam_attn_kernel<<<dim3(128, 4), 128, 0, stream>>>(ep, attnB);
    qkv_mfma_kernel<<<dim3(32, 4), 256, 0, stream>>>(Wqkv, biasAll, fT, qT, kT, vB);
    pam_mfma_kernel<<<dim3(4, 64, 4), 256, 0, stream>>>(qT, kT, vB, pamP);
    combine_kernel<<<dim3(32, 4), 256, 0, stream>>>(attnB, fT, featB, pamP, gca, gpa, out);
}

// Round 6
// 275.888 us; speedup vs baseline: 4.5868x; 1.0244x over previous
//
#include <hip/hip_runtime.h>
#include <math.h>

// Problem constants
#define BATCH 4
#define CIN   256
#define CCH   128      // Cout
#define HW    4096     // 64*64
#define CQK   16

using short8   = __attribute__((ext_vector_type(8))) short;
using floatx4  = __attribute__((ext_vector_type(4))) float;
using floatx16 = __attribute__((ext_vector_type(16))) float;

__device__ __forceinline__ float fast_tanh(float x) {
    float e = __expf(2.0f * x);
    return 1.0f - __fdividef(2.0f, e + 1.0f);
}

__device__ __forceinline__ unsigned short f2bf(float f) {
    unsigned u = __float_as_uint(f);
    u += 0x7fff + ((u >> 16) & 1);   // RNE
    return (unsigned short)(u >> 16);
}

__device__ __forceinline__ float bf2f(unsigned short u) {
    return __uint_as_float(((unsigned)u) << 16);
}

// C/D row map for mfma_f32_32x32x16: row = (r&3) + 8*(r>>2) + 4*hi, col = lane&31
#define ROWMAP(r, hi) (((r) & 3) + (((r) >> 2) << 3) + ((hi) << 2))

#define XTP_ROW   (66 * 256)          // shorts per padded row
#define XTP_BATCH (66 * 66 * 256)     // shorts per batch

// ---------------------------------------------------------------------------
// 0) transpose x [b][ci][y][x] fp32 -> xTp [b][y+1][x+1][ci] bf16, with halo
//    zeroing fused (cols 0/65 per row; rows 0/65 for edge y-blocks).
// grid(4 ci-tiles, 64 y, 4 b), block 256
// ---------------------------------------------------------------------------
__global__ __launch_bounds__(256) void xt_prep_kernel(
        const float* __restrict__ x, unsigned short* __restrict__ xTp) {
    __shared__ unsigned short lds[64][72];
    const int tid = threadIdx.x;
    const int ci0 = blockIdx.x * 64, yr = blockIdx.y, b = blockIdx.z;
    const int cir = tid >> 2, xc = tid & 3;
    const float* xp = x + (((b << 8) + ci0 + cir) << 12) + (yr << 6) + xc * 16;
#pragma unroll
    for (int j = 0; j < 4; ++j) {
        float4 v = *(const float4*)(xp + j * 4);
        int xi = xc * 16 + j * 4;
        lds[xi + 0][cir] = f2bf(v.x);
        lds[xi + 1][cir] = f2bf(v.y);
        lds[xi + 2][cir] = f2bf(v.z);
        lds[xi + 3][cir] = f2bf(v.w);
    }
    // halo: columns 0 and 65 of this row-slice
    const short8 z8 = (short8){0,0,0,0,0,0,0,0};
    if (tid < 16) {
        int col = (tid >> 3) ? 65 : 0;
        int part = tid & 7;
        *(short8*)(xTp + b * XTP_BATCH + (yr + 1) * XTP_ROW + col * 256 +
                   ci0 + part * 8) = z8;
    }
    // halo: full rows 0 / 65 (edge y-blocks only)
    if (yr == 0 || yr == 63) {
        int row = (yr == 0) ? 0 : 65;
        for (int e = tid; e < 528; e += 256) {     // 66 x * 8 ci-parts
            int xi = e >> 3, part = e & 7;
            *(short8*)(xTp + b * XTP_BATCH + row * XTP_ROW + xi * 256 +
                       ci0 + part * 8) = z8;
        }
    }
    __syncthreads();
    const int xr = tid >> 2, part = tid & 3;
    unsigned short* dst = xTp + b * XTP_BATCH + (yr + 1) * XTP_ROW +
                          (xr + 1) * 256 + ci0 + part * 16;
    *(short8*)(dst + 0) = *(const short8*)&lds[xr][part * 16 + 0];
    *(short8*)(dst + 8) = *(const short8*)&lds[xr][part * 16 + 8];
}

// ---------------------------------------------------------------------------
// 1) Fused weight prep:
//    blocks [0,1152): w[co][ci][3][3] fp32 -> Wb2[tap][cc][co][s] bf16
//    blocks [1152,1232): q/k/v weights -> Wqkv[160][128] bf16 + biasAll[160]
// ---------------------------------------------------------------------------
__global__ __launch_bounds__(256) void prep_kernel(
        const float* __restrict__ w,
        const float* __restrict__ qw, const float* __restrict__ qb,
        const float* __restrict__ kw, const float* __restrict__ kb,
        const float* __restrict__ vw, const float* __restrict__ vb,
        unsigned short* __restrict__ Wb2, unsigned short* __restrict__ Wqkv,
        float* __restrict__ biasAll) {
    if (blockIdx.x < 1152) {
        int o = blockIdx.x * 256 + threadIdx.x;          // < 294912
        int s   = o & 31;
        int co  = (o >> 5) & 127;
        int cc  = (o >> 12) & 7;
        int tap = o >> 15;
        int ci  = (cc << 5) + s;
        Wb2[o] = f2bf(w[co * 2304 + ci * 9 + tap]);
    } else {
        int idx = (blockIdx.x - 1152) * 256 + threadIdx.x;   // < 20480
        int o = idx >> 7, c = idx & 127;
        float wv = (o < 16) ? qw[(o << 7) + c]
                 : (o < 32) ? kw[((o - 16) << 7) + c]
                            : vw[((o - 32) << 7) + c];
        Wqkv[idx] = f2bf(wv);
        if (idx < 160)
            biasAll[idx] = (idx < 16) ? qb[idx] : (idx < 32) ? kb[idx - 16] : vb[idx - 32];
    }
}

// ---------------------------------------------------------------------------
// 2) Conv implicit GEMM, bf16 MFMA 16x16x32 — LDS-free, barrier-free.
// grid(2, 64, 4) = 512 blocks, block 256.
// ---------------------------------------------------------------------------
__global__ __launch_bounds__(256) void conv_mfma_kernel(
        const unsigned short* __restrict__ xTp, const unsigned short* __restrict__ Wb2,
        float* __restrict__ y) {
    const int tid = threadIdx.x;
    const int w = tid >> 6, lane = tid & 63, l15 = lane & 15, quad = lane >> 4;
    const int x0 = blockIdx.x * 32, yr = blockIdx.y, b = blockIdx.z;

    floatx4 acc[2][2];
#pragma unroll
    for (int i = 0; i < 2; ++i)
#pragma unroll
        for (int j = 0; j < 2; ++j) acc[i][j] = (floatx4){0.f, 0.f, 0.f, 0.f};

    const unsigned short* xb = xTp + b * XTP_BATCH + yr * XTP_ROW;
    const int aco0 = (w << 5) + l15;

#pragma unroll
    for (int ky = 0; ky < 3; ++ky) {
#pragma unroll
        for (int kx = 0; kx < 3; ++kx) {
            const unsigned short* arow = Wb2 + ((ky * 3 + kx) << 15);
            const unsigned short* brow = xb + ky * XTP_ROW + (x0 + kx) * 256;
#pragma unroll
            for (int cc = 0; cc < 8; ++cc) {
                short8 a0 = *(const short8*)(arow + (((cc << 7) + aco0) << 5) + quad * 8);
                short8 a1 = *(const short8*)(arow + (((cc << 7) + aco0 + 16) << 5) + quad * 8);
                short8 b0 = *(const short8*)(brow + (l15 << 8) + (cc << 5) + quad * 8);
                short8 b1 = *(const short8*)(brow + ((16 + l15) << 8) + (cc << 5) + quad * 8);
                acc[0][0] = __builtin_amdgcn_mfma_f32_16x16x32_bf16(a0, b0, acc[0][0], 0, 0, 0);
                acc[0][1] = __builtin_amdgcn_mfma_f32_16x16x32_bf16(a0, b1, acc[0][1], 0, 0, 0);
                acc[1][0] = __builtin_amdgcn_mfma_f32_16x16x32_bf16(a1, b0, acc[1][0], 0, 0, 0);
                acc[1][1] = __builtin_amdgcn_mfma_f32_16x16x32_bf16(a1, b1, acc[1][1], 0, 0, 0);
            }
        }
    }

#pragma unroll
    for (int ms = 0; ms < 2; ++ms)
#pragma unroll
        for (int ns = 0; ns < 2; ++ns) {
            int px = x0 + ns * 16 + l15;
#pragma unroll
            for (int r = 0; r < 4; ++r) {
                int co = (w << 5) + ms * 16 + quad * 4 + r;
                y[(((b << 7) + co) << 12) + (yr << 6) + px] = acc[ms][ns][r];
            }
        }
}

// ---------------------------------------------------------------------------
// 3) BN stats per channel -> fused scale/shift. grid(128), block 256
// ---------------------------------------------------------------------------
__global__ __launch_bounds__(256) void bn_stats_kernel(
        const float* __restrict__ y, const float* __restrict__ gamma,
        const float* __restrict__ beta, float* __restrict__ scale,
        float* __restrict__ shift) {
    const int c = blockIdx.x, tid = threadIdx.x;
    float s = 0.f, q = 0.f;
    for (int i = tid; i < BATCH * HW; i += 256) {
        float v = y[((((i >> 12) << 7) + c) << 12) + (i & 4095)];
        s += v; q += v * v;
    }
    for (int off = 32; off; off >>= 1) {
        s += __shfl_down(s, off);
        q += __shfl_down(q, off);
    }
    __shared__ float ls[4], lq[4];
    if ((tid & 63) == 0) { ls[tid >> 6] = s; lq[tid >> 6] = q; }
    __syncthreads();
    if (tid == 0) {
        float S = ls[0] + ls[1] + ls[2] + ls[3];
        float Q = lq[0] + lq[1] + lq[2] + lq[3];
        float mean = S * (1.f / 16384.f);
        float var  = Q * (1.f / 16384.f) - mean * mean;
        float rstd = rsqrtf(var + 1e-5f);
        float sc = gamma[c] * rstd;
        scale[c] = sc;
        shift[c] = beta[c] - mean * sc;
    }
}

// ---------------------------------------------------------------------------
// 4) BN apply + ReLU -> featB bf16 [b][c][n] and fT bf16 [b][n][c].
// ---------------------------------------------------------------------------
__global__ __launch_bounds__(256) void bn_apply_kernel(
        const float* __restrict__ y, const float* __restrict__ scale,
        const float* __restrict__ shift, unsigned short* __restrict__ featB,
        unsigned short* __restrict__ fT) {
    int base = (blockIdx.x * 256 + threadIdx.x) * 4;
    int b = base >> 19, c = (base >> 12) & 127, n = base & 4095;
    float sc = scale[c], sh = shift[c];
    float4 v = *(const float4*)&y[base];
    float f0 = fmaxf(fmaf(v.x, sc, sh), 0.f);
    float f1 = fmaxf(fmaf(v.y, sc, sh), 0.f);
    float f2 = fmaxf(fmaf(v.z, sc, sh), 0.f);
    float f3 = fmaxf(fmaf(v.w, sc, sh), 0.f);
    ushort4 o;
    o.x = f2bf(f0); o.y = f2bf(f1); o.z = f2bf(f2); o.w = f2bf(f3);
    *(ushort4*)&featB[base] = o;
    fT[(((b << 12) + n + 0) << 7) + c] = o.x;
    fT[(((b << 12) + n + 1) << 7) + c] = o.y;
    fT[(((b << 12) + n + 2) << 7) + c] = o.z;
    fT[(((b << 12) + n + 3) << 7) + c] = o.w;
}

// ---------------------------------------------------------------------------
// 5) CAM energy via MFMA, split-K 32, plain partial stores.
// grid(32, 4), block 256 -> ep[kc][b][c][d] fp32
// ---------------------------------------------------------------------------
__global__ __launch_bounds__(256) void cam_energy_mfma_kernel(
        const unsigned short* __restrict__ featB, float* __restrict__ ep) {
    const int b = blockIdx.y, kc = blockIdx.x, tid = threadIdx.x;
    const int wv = tid >> 6, l31 = tid & 31, hi = (tid >> 5) & 1;
    floatx16 acc[4];
#pragma unroll
    for (int t = 0; t < 4; ++t)
#pragma unroll
        for (int r = 0; r < 16; ++r) acc[t][r] = 0.f;

    for (int s = 0; s < 8; ++s) {
        const int k0 = (kc << 7) + (s << 4) + (hi << 3);
        short8 fr = *(const short8*)&featB[(((b << 7) + (wv << 5) + l31) << 12) + k0];
        short8 fc0 = *(const short8*)&featB[(((b << 7) +  0 + l31) << 12) + k0];
        short8 fc1 = *(const short8*)&featB[(((b << 7) + 32 + l31) << 12) + k0];
        short8 fc2 = *(const short8*)&featB[(((b << 7) + 64 + l31) << 12) + k0];
        short8 fc3 = *(const short8*)&featB[(((b << 7) + 96 + l31) << 12) + k0];
        acc[0] = __builtin_amdgcn_mfma_f32_32x32x16_bf16(fr, fc0, acc[0], 0, 0, 0);
        acc[1] = __builtin_amdgcn_mfma_f32_32x32x16_bf16(fr, fc1, acc[1], 0, 0, 0);
        acc[2] = __builtin_amdgcn_mfma_f32_32x32x16_bf16(fr, fc2, acc[2], 0, 0, 0);
        acc[3] = __builtin_amdgcn_mfma_f32_32x32x16_bf16(fr, fc3, acc[3], 0, 0, 0);
    }
#pragma unroll
    for (int t = 0; t < 4; ++t)
#pragma unroll
        for (int r = 0; r < 16; ++r) {
            int c = (wv << 5) + ROWMAP(r, hi);
            int d = (t << 5) + l31;
            ep[(((kc << 2) + b) << 14) + (c << 7) + d] = acc[t][r];
        }
}

// 6) CAM attn: sum 32 partials, attnB = bf16(tanh(rowmax - e)). grid(128,4)
__global__ __launch_bounds__(128) void cam_attn_kernel(
        const float* __restrict__ ep, unsigned short* __restrict__ attnB) {
    const int b = blockIdx.y, c = blockIdx.x, tid = threadIdx.x;
    float v = 0.f;
#pragma unroll
    for (int s = 0; s < 32; ++s)
        v += ep[(((s << 2) + b) << 14) + (c << 7) + tid];
    float m = v;
    for (int off = 32; off; off >>= 1) m = fmaxf(m, __shfl_down(m, off));
    __shared__ float mx[2];
    if ((tid & 63) == 0) mx[tid >> 6] = m;
    __syncthreads();
    float M = fmaxf(mx[0], mx[1]);
    attnB[(b << 14) + (c << 7) + tid] = f2bf(fast_tanh(M - v));
}

// ---------------------------------------------------------------------------
// 7) QKV via MFMA. grid(32 ntiles, 4 b), block 256.
// ---------------------------------------------------------------------------
__global__ __launch_bounds__(256) void qkv_mfma_kernel(
        const unsigned short* __restrict__ Wqkv, const float* __restrict__ biasAll,
        const unsigned short* __restrict__ fT,
        unsigned short* __restrict__ qT, unsigned short* __restrict__ kT,
        unsigned short* __restrict__ vB) {
    const int b = blockIdx.y, tid = threadIdx.x;
    const int wv = tid >> 6, l31 = tid & 31, hi = (tid >> 5) & 1;
    const int n0 = (blockIdx.x << 7) + (wv << 5);
    floatx16 acc[5];
#pragma unroll
    for (int t = 0; t < 5; ++t)
#pragma unroll
        for (int r = 0; r < 16; ++r) acc[t][r] = 0.f;

    for (int s = 0; s < 8; ++s) {
        const int k0 = (s << 4) + (hi << 3);
        short8 bf = *(const short8*)&fT[(((b << 12) + n0 + l31) << 7) + k0];
#pragma unroll
        for (int t = 0; t < 5; ++t) {
            short8 aw = *(const short8*)&Wqkv[(((t << 5) + l31) << 7) + k0];
            acc[t] = __builtin_amdgcn_mfma_f32_32x32x16_bf16(aw, bf, acc[t], 0, 0, 0);
        }
    }
    const int n = n0 + l31;
#pragma unroll
    for (int t = 0; t < 5; ++t)
#pragma unroll
        for (int r = 0; r < 16; ++r) {
            int o = (t << 5) + ROWMAP(r, hi);
            float val = acc[t][r] + biasAll[o];
            if (t == 0) {
                if (o < 16) qT[(((b << 12) + n) << 4) + o] = f2bf(val);
                else        kT[(((b << 12) + n) << 4) + o - 16] = f2bf(val);
            } else if (o >= 32) {
                vB[(((b << 7) + o - 32) << 12) + n] = f2bf(val);
            }
        }
}

// ---------------------------------------------------------------------------
// 8) PAM via MFMA 32x32x16 bf16, flash-style, 8 blocks/CU.
//    Block = (b, 32-m tile, n-quarter 1024). Wave = c-quarter(32) x full m(32).
//    Per 128-n chunk: each wave computes its 32n x 32m S tile (1 MFMA, K=16),
//    tanh -> bf16 pairs -> double-buffered swizzled LDS attn[32m][128n];
//    one barrier; 8 PV MFMAs. Partials -> pamP (plain stores).
// grid(4, 128, 4) = 2048 blocks, block 256.
// ---------------------------------------------------------------------------
__global__ __launch_bounds__(256, 8) void pam_mfma_kernel(
        const unsigned short* __restrict__ qT, const unsigned short* __restrict__ kT,
        const unsigned short* __restrict__ vB, unsigned short* __restrict__ pamP) {
    __shared__ unsigned short attn_s[2][32 * 128];   // 16 KB double buffer
    const int b  = blockIdx.z, m0 = blockIdx.y * 32, nh = blockIdx.x;
    const int tid = threadIdx.x;
    const int w = tid >> 6, lane = tid & 63, l31 = lane & 31, hi = lane >> 5;
    const int ch = w << 5;             // c-quarter base

    short8 bq = *(const short8*)&qT[(((b << 12) + m0 + l31) << 4) + hi * 8];

    floatx16 acc, zero16;
#pragma unroll
    for (int r = 0; r < 16; ++r) { acc[r] = 0.f; zero16[r] = 0.f; }

    short8 ak = *(const short8*)&kT[(((b << 12) + (nh << 10) + (w << 5) + l31) << 4) + hi * 8];

    const int mwr  = l31;              // write row (= col of S output)
    const int msww = mwr & 15;
    const int mrow = mwr << 7;

    for (int nc = 0; nc < 8; ++nc) {
        const int na = (nh << 10) + (nc << 7);     // chunk base n
        unsigned short* buf = attn_s[nc & 1];
        floatx16 s0 = __builtin_amdgcn_mfma_f32_32x32x16_bf16(ak, bq, zero16, 0, 0, 0);
        // prefetch next chunk's K fragment under the tanh phase
        short8 ak_n = ak;
        if (nc < 7)
            ak_n = *(const short8*)&kT[(((b << 12) + na + 128 + (w << 5) + l31) << 4) + hi * 8];
#pragma unroll
        for (int p = 0; p < 8; ++p) {
            float t0 = fast_tanh(s0[2 * p]);
            float t1 = fast_tanh(s0[2 * p + 1]);
            unsigned u = (__float_as_uint(t1) & 0xFFFF0000u) |
                         (__float_as_uint(t0) >> 16);
            int n = (w << 5) + (p & 1) * 2 + ((p >> 1) << 3) + hi * 4;  // even
            int idx = mrow + ((((n >> 3) ^ msww) << 3) + (n & 7));
            *(unsigned*)&buf[idx] = u;
        }
        __syncthreads();
#pragma unroll
        for (int ks = 0; ks < 8; ++ks) {
            short8 ba = *(const short8*)&buf[mrow + (((ks * 2 + hi) ^ msww) << 3)];
            short8 av = *(const short8*)&vB[(((b << 7) + ch + l31) << 12) + na + ks * 16 + hi * 8];
            acc = __builtin_amdgcn_mfma_f32_32x32x16_bf16(av, ba, acc, 0, 0, 0);
        }
        ak = ak_n;
    }
    const int pbase = (((nh << 2) + b) << 19) + m0 + l31;
#pragma unroll
    for (int r = 0; r < 16; ++r) {
        int crow = ROWMAP(r, hi);
        pamP[pbase + ((ch + crow) << 12)] = f2bf(acc[r]);
    }
}

// ---------------------------------------------------------------------------
// 9) Combine: out = 3*feat + g_ca*(attn @ f) + g_pa*(sum pamP). grid(32,4)
// ---------------------------------------------------------------------------
__global__ __launch_bounds__(256) void combine_kernel(
        const unsigned short* __restrict__ attnB, const unsigned short* __restrict__ fT,
        const unsigned short* __restrict__ featB, const unsigned short* __restrict__ pamP,
        const float* __restrict__ gca, const float* __restrict__ gpa,
        float* __restrict__ out) {
    const int b = blockIdx.y, tid = threadIdx.x;
    const int wv = tid >> 6, l31 = tid & 31, hi = (tid >> 5) & 1;
    const int m0 = (blockIdx.x << 7) + (wv << 5);
    floatx16 acc[4];
#pragma unroll
    for (int t = 0; t < 4; ++t)
#pragma unroll
        for (int r = 0; r < 16; ++r) acc[t][r] = 0.f;

    for (int s = 0; s < 8; ++s) {
        const int k0 = (s << 4) + (hi << 3);
        short8 bf = *(const short8*)&fT[(((b << 12) + m0 + l31) << 7) + k0];
        short8 a0 = *(const short8*)&attnB[(b << 14) + (( 0 + l31) << 7) + k0];
        short8 a1 = *(const short8*)&attnB[(b << 14) + ((32 + l31) << 7) + k0];
        short8 a2 = *(const short8*)&attnB[(b << 14) + ((64 + l31) << 7) + k0];
        short8 a3 = *(const short8*)&attnB[(b << 14) + ((96 + l31) << 7) + k0];
        acc[0] = __builtin_amdgcn_mfma_f32_32x32x16_bf16(a0, bf, acc[0], 0, 0, 0);
        acc[1] = __builtin_amdgcn_mfma_f32_32x32x16_bf16(a1, bf, acc[1], 0, 0, 0);
        acc[2] = __builtin_amdgcn_mfma_f32_32x32x16_bf16(a2, bf, acc[2], 0, 0, 0);
        acc[3] = __builtin_amdgcn_mfma_f32_32x32x16_bf16(a3, bf, acc[3], 0, 0, 0);
    }
    const float gc = gca[0], gp = gpa[0];
    const int m = m0 + l31;
#pragma unroll
    for (int t = 0; t < 4; ++t)
#pragma unroll
        for (int r = 0; r < 16; ++r) {
            int c = (t << 5) + ROWMAP(r, hi);
            int ci = (c << 12) + m;
            float p = bf2f(pamP[((0 * 4 + b) << 19) + ci]) +
                      bf2f(pamP[((1 * 4 + b) << 19) + ci]) +
                      bf2f(pamP[((2 * 4 + b) << 19) + ci]) +
                      bf2f(pamP[((3 * 4 + b) << 19) + ci]);
            float fb = bf2f(featB[(((b << 7) + c) << 12) + m]);
            out[(((b << 7) + c) << 12) + m] = 3.f * fb + gc * acc[t][r] + gp * p;
        }
}

// ---------------------------------------------------------------------------
extern "C" void kernel_launch(void* const* d_in, const int* in_sizes, int n_in,
                              void* d_out, int out_size, void* d_ws, size_t ws_size,
                              hipStream_t stream) {
    const float* x      = (const float*)d_in[0];
    const float* conv_w = (const float*)d_in[1];
    const float* bn_g   = (const float*)d_in[2];
    const float* bn_b   = (const float*)d_in[3];
    const float* q_w    = (const float*)d_in[4];
    const float* q_b    = (const float*)d_in[5];
    const float* k_w    = (const float*)d_in[6];
    const float* k_b    = (const float*)d_in[7];
    const float* v_w    = (const float*)d_in[8];
    const float* v_b    = (const float*)d_in[9];
    const float* gca    = (const float*)d_in[10];
    const float* gpa    = (const float*)d_in[11];
    float* out = (float*)d_out;

    float* ws = (float*)d_ws;
    // layout (floats):
    float* convY  = ws;                                     // [0, 2,097,152)
    unsigned short* xTp = (unsigned short*)(ws + 2097152);  // -> [2,097,152, 4,327,424)
    float* ep     = ws + 4327424;                           // 2,097,152 f
    float* scale  = ws + 6424576;                           // 128
    float* shift  = ws + 6424704;                           // 128
    float* biasAll= ws + 6424832;                           // 256 (pad)
    unsigned short* Wb2   = (unsigned short*)(ws + 6425088); // 294,912 sh
    unsigned short* Wqkv  = (unsigned short*)(ws + 6572544); // 20,480 sh
    unsigned short* attnB = (unsigned short*)(ws + 6582784); // 65,536 sh
    unsigned short* qT    = (unsigned short*)(ws + 6615552); // 262,144 sh
    unsigned short* kT    = (unsigned short*)(ws + 6746624); // 262,144 sh
    unsigned short* vB    = (unsigned short*)(ws + 6877696); // 2,097,152 sh
    unsigned short* featB = (unsigned short*)(ws + 7926272); // 2,097,152 sh
    unsigned short* fT    = (unsigned short*)(ws + 8974848); // 2,097,152 sh
    // pamP bf16[4][4][128][4096] = 8,388,608 sh = 16.8 MB, ALIASES convY+xTp
    // (both dead by pam time; fully overwritten before combine reads it)
    unsigned short* pamP  = (unsigned short*)ws;

    xt_prep_kernel<<<dim3(4, 64, 4), 256, 0, stream>>>(x, xTp);
    prep_kernel<<<1232, 256, 0, stream>>>(conv_w, q_w, q_b, k_w, k_b, v_w, v_b,
                                          Wb2, Wqkv, biasAll);
    conv_mfma_kernel<<<dim3(2, 64, 4), 256, 0, stream>>>(xTp, Wb2, convY);
    bn_stats_kernel<<<128, 256, 0, stream>>>(convY, bn_g, bn_b, scale, shift);
    bn_apply_kernel<<<2048, 256, 0, stream>>>(convY, scale, shift, featB, fT);
    cam_energy_mfma_kernel<<<dim3(32, 4), 256, 0, stream>>>(featB, ep);
    cam_attn_kernel<<<dim3(128, 4), 128, 0, stream>>>(ep, attnB);
    qkv_mfma_kernel<<<dim3(32, 4), 256, 0, stream>>>(Wqkv, biasAll, fT, qT, kT, vB);
    pam_mfma_kernel<<<dim3(4, 128, 4), 256, 0, stream>>>(qT, kT, vB, pamP);
    combine_kernel<<<dim3(32, 4), 256, 0, stream>>>(attnB, fT, featB, pamP, gca, gpa, out);
}

// Round 7
// 263.662 us; speedup vs baseline: 4.7995x; 1.0464x over previous
//
#include <hip/hip_runtime.h>
#include <math.h>

// Problem constants
#define BATCH 4
#define CIN   256
#define CCH   128      // Cout
#define HW    4096     // 64*64
#define CQK   16

using short8   = __attribute__((ext_vector_type(8))) short;
using floatx4  = __attribute__((ext_vector_type(4))) float;
using floatx16 = __attribute__((ext_vector_type(16))) float;
using uint4v   = __attribute__((ext_vector_type(4))) unsigned int;

__device__ __forceinline__ float fast_tanh(float x) {
    float e = __expf(2.0f * x);
    return 1.0f - __fdividef(2.0f, e + 1.0f);
}

__device__ __forceinline__ unsigned short f2bf(float f) {
    unsigned u = __float_as_uint(f);
    u += 0x7fff + ((u >> 16) & 1);   // RNE
    return (unsigned short)(u >> 16);
}

__device__ __forceinline__ float bf2f(unsigned short u) {
    return __uint_as_float(((unsigned)u) << 16);
}

// C/D row map for mfma_f32_32x32x16: row = (r&3) + 8*(r>>2) + 4*hi, col = lane&31
#define ROWMAP(r, hi) (((r) & 3) + (((r) >> 2) << 3) + ((hi) << 2))

#define XTP_ROW   (66 * 256)          // shorts per padded row
#define XTP_BATCH (66 * 66 * 256)     // shorts per batch

// ---------------------------------------------------------------------------
// 0) transpose x [b][ci][y][x] fp32 -> xTp [b][y+1][x+1][ci] bf16, with halo
// grid(4 ci-tiles, 64 y, 4 b), block 256
// ---------------------------------------------------------------------------
__global__ __launch_bounds__(256) void xt_prep_kernel(
        const float* __restrict__ x, unsigned short* __restrict__ xTp) {
    __shared__ unsigned short lds[64][72];
    const int tid = threadIdx.x;
    const int ci0 = blockIdx.x * 64, yr = blockIdx.y, b = blockIdx.z;
    const int cir = tid >> 2, xc = tid & 3;
    const float* xp = x + (((b << 8) + ci0 + cir) << 12) + (yr << 6) + xc * 16;
#pragma unroll
    for (int j = 0; j < 4; ++j) {
        float4 v = *(const float4*)(xp + j * 4);
        int xi = xc * 16 + j * 4;
        lds[xi + 0][cir] = f2bf(v.x);
        lds[xi + 1][cir] = f2bf(v.y);
        lds[xi + 2][cir] = f2bf(v.z);
        lds[xi + 3][cir] = f2bf(v.w);
    }
    const short8 z8 = (short8){0,0,0,0,0,0,0,0};
    if (tid < 16) {
        int col = (tid >> 3) ? 65 : 0;
        int part = tid & 7;
        *(short8*)(xTp + b * XTP_BATCH + (yr + 1) * XTP_ROW + col * 256 +
                   ci0 + part * 8) = z8;
    }
    if (yr == 0 || yr == 63) {
        int row = (yr == 0) ? 0 : 65;
        for (int e = tid; e < 528; e += 256) {
            int xi = e >> 3, part = e & 7;
            *(short8*)(xTp + b * XTP_BATCH + row * XTP_ROW + xi * 256 +
                       ci0 + part * 8) = z8;
        }
    }
    __syncthreads();
    const int xr = tid >> 2, part = tid & 3;
    unsigned short* dst = xTp + b * XTP_BATCH + (yr + 1) * XTP_ROW +
                          (xr + 1) * 256 + ci0 + part * 16;
    *(short8*)(dst + 0) = *(const short8*)&lds[xr][part * 16 + 0];
    *(short8*)(dst + 8) = *(const short8*)&lds[xr][part * 16 + 8];
}

// ---------------------------------------------------------------------------
// 1) Fused weight prep (conv + qkv weights)
// ---------------------------------------------------------------------------
__global__ __launch_bounds__(256) void prep_kernel(
        const float* __restrict__ w,
        const float* __restrict__ qw, const float* __restrict__ qb,
        const float* __restrict__ kw, const float* __restrict__ kb,
        const float* __restrict__ vw, const float* __restrict__ vb,
        unsigned short* __restrict__ Wb2, unsigned short* __restrict__ Wqkv,
        float* __restrict__ biasAll) {
    if (blockIdx.x < 1152) {
        int o = blockIdx.x * 256 + threadIdx.x;          // < 294912
        int s   = o & 31;
        int co  = (o >> 5) & 127;
        int cc  = (o >> 12) & 7;
        int tap = o >> 15;
        int ci  = (cc << 5) + s;
        Wb2[o] = f2bf(w[co * 2304 + ci * 9 + tap]);
    } else {
        int idx = (blockIdx.x - 1152) * 256 + threadIdx.x;   // < 20480
        int o = idx >> 7, c = idx & 127;
        float wv = (o < 16) ? qw[(o << 7) + c]
                 : (o < 32) ? kw[((o - 16) << 7) + c]
                            : vw[((o - 32) << 7) + c];
        Wqkv[idx] = f2bf(wv);
        if (idx < 160)
            biasAll[idx] = (idx < 16) ? qb[idx] : (idx < 32) ? kb[idx - 16] : vb[idx - 32];
    }
}

// ---------------------------------------------------------------------------
// 2) Conv implicit GEMM, bf16 MFMA 16x16x32 — LDS-free, barrier-free.
// grid(2, 64, 4) = 512 blocks, block 256.
// ---------------------------------------------------------------------------
__global__ __launch_bounds__(256) void conv_mfma_kernel(
        const unsigned short* __restrict__ xTp, const unsigned short* __restrict__ Wb2,
        float* __restrict__ y) {
    const int tid = threadIdx.x;
    const int w = tid >> 6, lane = tid & 63, l15 = lane & 15, quad = lane >> 4;
    const int x0 = blockIdx.x * 32, yr = blockIdx.y, b = blockIdx.z;

    floatx4 acc[2][2];
#pragma unroll
    for (int i = 0; i < 2; ++i)
#pragma unroll
        for (int j = 0; j < 2; ++j) acc[i][j] = (floatx4){0.f, 0.f, 0.f, 0.f};

    const unsigned short* xb = xTp + b * XTP_BATCH + yr * XTP_ROW;
    const int aco0 = (w << 5) + l15;

#pragma unroll
    for (int ky = 0; ky < 3; ++ky) {
#pragma unroll
        for (int kx = 0; kx < 3; ++kx) {
            const unsigned short* arow = Wb2 + ((ky * 3 + kx) << 15);
            const unsigned short* brow = xb + ky * XTP_ROW + (x0 + kx) * 256;
#pragma unroll
            for (int cc = 0; cc < 8; ++cc) {
                short8 a0 = *(const short8*)(arow + (((cc << 7) + aco0) << 5) + quad * 8);
                short8 a1 = *(const short8*)(arow + (((cc << 7) + aco0 + 16) << 5) + quad * 8);
                short8 b0 = *(const short8*)(brow + (l15 << 8) + (cc << 5) + quad * 8);
                short8 b1 = *(const short8*)(brow + ((16 + l15) << 8) + (cc << 5) + quad * 8);
                acc[0][0] = __builtin_amdgcn_mfma_f32_16x16x32_bf16(a0, b0, acc[0][0], 0, 0, 0);
                acc[0][1] = __builtin_amdgcn_mfma_f32_16x16x32_bf16(a0, b1, acc[0][1], 0, 0, 0);
                acc[1][0] = __builtin_amdgcn_mfma_f32_16x16x32_bf16(a1, b0, acc[1][0], 0, 0, 0);
                acc[1][1] = __builtin_amdgcn_mfma_f32_16x16x32_bf16(a1, b1, acc[1][1], 0, 0, 0);
            }
        }
    }

#pragma unroll
    for (int ms = 0; ms < 2; ++ms)
#pragma unroll
        for (int ns = 0; ns < 2; ++ns) {
            int px = x0 + ns * 16 + l15;
#pragma unroll
            for (int r = 0; r < 4; ++r) {
                int co = (w << 5) + ms * 16 + quad * 4 + r;
                y[(((b << 7) + co) << 12) + (yr << 6) + px] = acc[ms][ns][r];
            }
        }
}

// ---------------------------------------------------------------------------
// 3) BN stats per channel -> fused scale/shift. grid(128), block 256
// ---------------------------------------------------------------------------
__global__ __launch_bounds__(256) void bn_stats_kernel(
        const float* __restrict__ y, const float* __restrict__ gamma,
        const float* __restrict__ beta, float* __restrict__ scale,
        float* __restrict__ shift) {
    const int c = blockIdx.x, tid = threadIdx.x;
    float s = 0.f, q = 0.f;
    for (int i = tid; i < BATCH * HW; i += 256) {
        float v = y[((((i >> 12) << 7) + c) << 12) + (i & 4095)];
        s += v; q += v * v;
    }
    for (int off = 32; off; off >>= 1) {
        s += __shfl_down(s, off);
        q += __shfl_down(q, off);
    }
    __shared__ float ls[4], lq[4];
    if ((tid & 63) == 0) { ls[tid >> 6] = s; lq[tid >> 6] = q; }
    __syncthreads();
    if (tid == 0) {
        float S = ls[0] + ls[1] + ls[2] + ls[3];
        float Q = lq[0] + lq[1] + lq[2] + lq[3];
        float mean = S * (1.f / 16384.f);
        float var  = Q * (1.f / 16384.f) - mean * mean;
        float rstd = rsqrtf(var + 1e-5f);
        float sc = gamma[c] * rstd;
        scale[c] = sc;
        shift[c] = beta[c] - mean * sc;
    }
}

// ---------------------------------------------------------------------------
// 4) BN apply + ReLU -> featB [b][c][n] (coalesced) and fT [b][n][c] via
//    LDS-transposed 64x64 tiles (xt_prep pattern; kills the 2B scatter).
// grid(2 c-tiles, 64 n-tiles, 4 b), block 256
// ---------------------------------------------------------------------------
__global__ __launch_bounds__(256) void bn_apply_kernel(
        const float* __restrict__ y, const float* __restrict__ scale,
        const float* __restrict__ shift, unsigned short* __restrict__ featB,
        unsigned short* __restrict__ fT) {
    __shared__ unsigned short lds[64][72];
    const int tid = threadIdx.x;
    const int c0 = blockIdx.x * 64, n0 = blockIdx.y * 64, b = blockIdx.z;
    const int cir = tid >> 2, xc = tid & 3;
    const float sc = scale[c0 + cir], sh = shift[c0 + cir];
    const float* yp = y + (((b << 7) + c0 + cir) << 12) + n0 + xc * 16;
    unsigned short* fp = featB + (((b << 7) + c0 + cir) << 12) + n0 + xc * 16;
#pragma unroll
    for (int j = 0; j < 4; ++j) {
        float4 v = *(const float4*)(yp + j * 4);
        ushort4 o;
        o.x = f2bf(fmaxf(fmaf(v.x, sc, sh), 0.f));
        o.y = f2bf(fmaxf(fmaf(v.y, sc, sh), 0.f));
        o.z = f2bf(fmaxf(fmaf(v.z, sc, sh), 0.f));
        o.w = f2bf(fmaxf(fmaf(v.w, sc, sh), 0.f));
        *(ushort4*)(fp + j * 4) = o;
        int ni = xc * 16 + j * 4;
        lds[ni + 0][cir] = o.x;
        lds[ni + 1][cir] = o.y;
        lds[ni + 2][cir] = o.z;
        lds[ni + 3][cir] = o.w;
    }
    __syncthreads();
    const int nr = tid >> 2, part = tid & 3;
    unsigned short* dst = fT + (((b << 12) + n0 + nr) << 7) + c0 + part * 16;
    *(short8*)(dst + 0) = *(const short8*)&lds[nr][part * 16 + 0];
    *(short8*)(dst + 8) = *(const short8*)&lds[nr][part * 16 + 8];
}

// ---------------------------------------------------------------------------
// 5) CAM energy via MFMA, split-K 32, plain partial stores.
// grid(32, 4), block 256 -> ep[kc][b][c][d] fp32
// ---------------------------------------------------------------------------
__global__ __launch_bounds__(256) void cam_energy_mfma_kernel(
        const unsigned short* __restrict__ featB, float* __restrict__ ep) {
    const int b = blockIdx.y, kc = blockIdx.x, tid = threadIdx.x;
    const int wv = tid >> 6, l31 = tid & 31, hi = (tid >> 5) & 1;
    floatx16 acc[4];
#pragma unroll
    for (int t = 0; t < 4; ++t)
#pragma unroll
        for (int r = 0; r < 16; ++r) acc[t][r] = 0.f;

    for (int s = 0; s < 8; ++s) {
        const int k0 = (kc << 7) + (s << 4) + (hi << 3);
        short8 fr = *(const short8*)&featB[(((b << 7) + (wv << 5) + l31) << 12) + k0];
        short8 fc0 = *(const short8*)&featB[(((b << 7) +  0 + l31) << 12) + k0];
        short8 fc1 = *(const short8*)&featB[(((b << 7) + 32 + l31) << 12) + k0];
        short8 fc2 = *(const short8*)&featB[(((b << 7) + 64 + l31) << 12) + k0];
        short8 fc3 = *(const short8*)&featB[(((b << 7) + 96 + l31) << 12) + k0];
        acc[0] = __builtin_amdgcn_mfma_f32_32x32x16_bf16(fr, fc0, acc[0], 0, 0, 0);
        acc[1] = __builtin_amdgcn_mfma_f32_32x32x16_bf16(fr, fc1, acc[1], 0, 0, 0);
        acc[2] = __builtin_amdgcn_mfma_f32_32x32x16_bf16(fr, fc2, acc[2], 0, 0, 0);
        acc[3] = __builtin_amdgcn_mfma_f32_32x32x16_bf16(fr, fc3, acc[3], 0, 0, 0);
    }
#pragma unroll
    for (int t = 0; t < 4; ++t)
#pragma unroll
        for (int r = 0; r < 16; ++r) {
            int c = (wv << 5) + ROWMAP(r, hi);
            int d = (t << 5) + l31;
            ep[(((kc << 2) + b) << 14) + (c << 7) + d] = acc[t][r];
        }
}

// 6) CAM attn: sum 32 partials, attnB = bf16(tanh(rowmax - e)). grid(128,4)
__global__ __launch_bounds__(128) void cam_attn_kernel(
        const float* __restrict__ ep, unsigned short* __restrict__ attnB) {
    const int b = blockIdx.y, c = blockIdx.x, tid = threadIdx.x;
    float v = 0.f;
#pragma unroll
    for (int s = 0; s < 32; ++s)
        v += ep[(((s << 2) + b) << 14) + (c << 7) + tid];
    float m = v;
    for (int off = 32; off; off >>= 1) m = fmaxf(m, __shfl_down(m, off));
    __shared__ float mx[2];
    if ((tid & 63) == 0) mx[tid >> 6] = m;
    __syncthreads();
    float M = fmaxf(mx[0], mx[1]);
    attnB[(b << 14) + (c << 7) + tid] = f2bf(fast_tanh(M - v));
}

// ---------------------------------------------------------------------------
// 7) QKV via MFMA. grid(32 ntiles, 4 b), block 256.
// ---------------------------------------------------------------------------
__global__ __launch_bounds__(256) void qkv_mfma_kernel(
        const unsigned short* __restrict__ Wqkv, const float* __restrict__ biasAll,
        const unsigned short* __restrict__ fT,
        unsigned short* __restrict__ qT, unsigned short* __restrict__ kT,
        unsigned short* __restrict__ vB) {
    const int b = blockIdx.y, tid = threadIdx.x;
    const int wv = tid >> 6, l31 = tid & 31, hi = (tid >> 5) & 1;
    const int n0 = (blockIdx.x << 7) + (wv << 5);
    floatx16 acc[5];
#pragma unroll
    for (int t = 0; t < 5; ++t)
#pragma unroll
        for (int r = 0; r < 16; ++r) acc[t][r] = 0.f;

    for (int s = 0; s < 8; ++s) {
        const int k0 = (s << 4) + (hi << 3);
        short8 bf = *(const short8*)&fT[(((b << 12) + n0 + l31) << 7) + k0];
#pragma unroll
        for (int t = 0; t < 5; ++t) {
            short8 aw = *(const short8*)&Wqkv[(((t << 5) + l31) << 7) + k0];
            acc[t] = __builtin_amdgcn_mfma_f32_32x32x16_bf16(aw, bf, acc[t], 0, 0, 0);
        }
    }
    const int n = n0 + l31;
#pragma unroll
    for (int t = 0; t < 5; ++t)
#pragma unroll
        for (int r = 0; r < 16; ++r) {
            int o = (t << 5) + ROWMAP(r, hi);
            float val = acc[t][r] + biasAll[o];
            if (t == 0) {
                if (o < 16) qT[(((b << 12) + n) << 4) + o] = f2bf(val);
                else        kT[(((b << 12) + n) << 4) + o - 16] = f2bf(val);
            } else if (o >= 32) {
                vB[(((b << 7) + o - 32) << 12) + n] = f2bf(val);
            }
        }
}

// ---------------------------------------------------------------------------
// 8) PAM via MFMA 32x32x16 bf16 — wave-autonomous: NO LDS, NO barriers.
//    Wave = (32 m, all 128 c), iterates its n-quarter in 32-n chunks.
//    S C-layout -> PV B-layout needs only a hi-half swap: 8 shfl_xor(32)
//    + 8 cndmask per chunk (replaces LDS roundtrip + 2 barriers).
// grid(4 nq, 32, 4) = 512 blocks, block 256.
// ---------------------------------------------------------------------------
__global__ __launch_bounds__(256, 2) void pam_mfma_kernel(
        const unsigned short* __restrict__ qT, const unsigned short* __restrict__ kT,
        const unsigned short* __restrict__ vB, unsigned short* __restrict__ pamP) {
    const int b = blockIdx.z, nh = blockIdx.x;
    const int tid = threadIdx.x;
    const int w = tid >> 6, lane = tid & 63, l31 = lane & 31, hi = lane >> 5;
    const int m0 = (blockIdx.y << 7) + (w << 5);

    // loop-invariant Q fragment (B operand of S): lane(m=l31, hi) k=hi*8+j
    short8 bq = *(const short8*)&qT[(((b << 12) + m0 + l31) << 4) + hi * 8];

    floatx16 acc[4], zero16;
#pragma unroll
    for (int r = 0; r < 16; ++r) {
        acc[0][r] = 0.f; acc[1][r] = 0.f; acc[2][r] = 0.f; acc[3][r] = 0.f;
        zero16[r] = 0.f;
    }

    const int nbase = nh << 10;
    short8 ak = *(const short8*)&kT[(((b << 12) + nbase + l31) << 4) + hi * 8];

    for (int nc = 0; nc < 32; ++nc) {
        const int na = nbase + (nc << 5);
        // V fragments for this chunk (issued early; consumed after tanh)
        short8 av[8];
#pragma unroll
        for (int ct = 0; ct < 4; ++ct) {
            const unsigned short* vp = vB + (((b << 7) + (ct << 5) + l31) << 12) + na + hi * 8;
            av[2 * ct]     = *(const short8*)(vp);
            av[2 * ct + 1] = *(const short8*)(vp + 16);
        }
        // S[n][m] for this wave's 32n x 32m
        floatx16 s = __builtin_amdgcn_mfma_f32_32x32x16_bf16(ak, bq, zero16, 0, 0, 0);
        if (nc < 31)
            ak = *(const short8*)&kT[(((b << 12) + na + 32 + l31) << 4) + hi * 8];
        // tanh + pack bf16 pairs (truncation; |attn|<=1 so err <= 0.004)
        unsigned p[8];
#pragma unroll
        for (int i = 0; i < 8; ++i) {
            float t0 = fast_tanh(s[2 * i]);
            float t1 = fast_tanh(s[2 * i + 1]);
            p[i] = (__float_as_uint(t1) & 0xFFFF0000u) | (__float_as_uint(t0) >> 16);
        }
        // hi-half swap: C-layout -> B-operand layout
        unsigned sh[8];
#pragma unroll
        for (int i = 0; i < 8; ++i) sh[i] = __shfl_xor(p[i], 32, 64);
        uint4v b1u, b2u;
        b1u[0] = hi ? sh[2] : p[0];
        b1u[1] = hi ? sh[3] : p[1];
        b1u[2] = hi ? p[2] : sh[0];
        b1u[3] = hi ? p[3] : sh[1];
        b2u[0] = hi ? sh[6] : p[4];
        b2u[1] = hi ? sh[7] : p[5];
        b2u[2] = hi ? p[6] : sh[4];
        b2u[3] = hi ? p[7] : sh[5];
        short8 B1 = __builtin_bit_cast(short8, b1u);
        short8 B2 = __builtin_bit_cast(short8, b2u);
        // PV: acc[c][m] += V[c][n] * attn[n][m]
#pragma unroll
        for (int ct = 0; ct < 4; ++ct) {
            acc[ct] = __builtin_amdgcn_mfma_f32_32x32x16_bf16(av[2 * ct], B1, acc[ct], 0, 0, 0);
            acc[ct] = __builtin_amdgcn_mfma_f32_32x32x16_bf16(av[2 * ct + 1], B2, acc[ct], 0, 0, 0);
        }
    }
    const int pbase = (((nh << 2) + b) << 19) + m0 + l31;
#pragma unroll
    for (int ct = 0; ct < 4; ++ct)
#pragma unroll
        for (int r = 0; r < 16; ++r) {
            int c = (ct << 5) + ROWMAP(r, hi);
            pamP[pbase + (c << 12)] = f2bf(acc[ct][r]);
        }
}

// ---------------------------------------------------------------------------
// 9) Combine: out = 3*feat + g_ca*(attn @ f) + g_pa*(sum pamP). grid(32,4)
// ---------------------------------------------------------------------------
__global__ __launch_bounds__(256) void combine_kernel(
        const unsigned short* __restrict__ attnB, const unsigned short* __restrict__ fT,
        const unsigned short* __restrict__ featB, const unsigned short* __restrict__ pamP,
        const float* __restrict__ gca, const float* __restrict__ gpa,
        float* __restrict__ out) {
    const int b = blockIdx.y, tid = threadIdx.x;
    const int wv = tid >> 6, l31 = tid & 31, hi = (tid >> 5) & 1;
    const int m0 = (blockIdx.x << 7) + (wv << 5);
    floatx16 acc[4];
#pragma unroll
    for (int t = 0; t < 4; ++t)
#pragma unroll
        for (int r = 0; r < 16; ++r) acc[t][r] = 0.f;

    for (int s = 0; s < 8; ++s) {
        const int k0 = (s << 4) + (hi << 3);
        short8 bf = *(const short8*)&fT[(((b << 12) + m0 + l31) << 7) + k0];
        short8 a0 = *(const short8*)&attnB[(b << 14) + (( 0 + l31) << 7) + k0];
        short8 a1 = *(const short8*)&attnB[(b << 14) + ((32 + l31) << 7) + k0];
        short8 a2 = *(const short8*)&attnB[(b << 14) + ((64 + l31) << 7) + k0];
        short8 a3 = *(const short8*)&attnB[(b << 14) + ((96 + l31) << 7) + k0];
        acc[0] = __builtin_amdgcn_mfma_f32_32x32x16_bf16(a0, bf, acc[0], 0, 0, 0);
        acc[1] = __builtin_amdgcn_mfma_f32_32x32x16_bf16(a1, bf, acc[1], 0, 0, 0);
        acc[2] = __builtin_amdgcn_mfma_f32_32x32x16_bf16(a2, bf, acc[2], 0, 0, 0);
        acc[3] = __builtin_amdgcn_mfma_f32_32x32x16_bf16(a3, bf, acc[3], 0, 0, 0);
    }
    const float gc = gca[0], gp = gpa[0];
    const int m = m0 + l31;
#pragma unroll
    for (int t = 0; t < 4; ++t)
#pragma unroll
        for (int r = 0; r < 16; ++r) {
            int c = (t << 5) + ROWMAP(r, hi);
            int ci = (c << 12) + m;
            float p = bf2f(pamP[((0 * 4 + b) << 19) + ci]) +
                      bf2f(pamP[((1 * 4 + b) << 19) + ci]) +
                      bf2f(pamP[((2 * 4 + b) << 19) + ci]) +
                      bf2f(pamP[((3 * 4 + b) << 19) + ci]);
            float fb = bf2f(featB[(((b << 7) + c) << 12) + m]);
            out[(((b << 7) + c) << 12) + m] = 3.f * fb + gc * acc[t][r] + gp * p;
        }
}

// ---------------------------------------------------------------------------
extern "C" void kernel_launch(void* const* d_in, const int* in_sizes, int n_in,
                              void* d_out, int out_size, void* d_ws, size_t ws_size,
                              hipStream_t stream) {
    const float* x      = (const float*)d_in[0];
    const float* conv_w = (const float*)d_in[1];
    const float* bn_g   = (const float*)d_in[2];
    const float* bn_b   = (const float*)d_in[3];
    const float* q_w    = (const float*)d_in[4];
    const float* q_b    = (const float*)d_in[5];
    const float* k_w    = (const float*)d_in[6];
    const float* k_b    = (const float*)d_in[7];
    const float* v_w    = (const float*)d_in[8];
    const float* v_b    = (const float*)d_in[9];
    const float* gca    = (const float*)d_in[10];
    const float* gpa    = (const float*)d_in[11];
    float* out = (float*)d_out;

    float* ws = (float*)d_ws;
    float* convY  = ws;                                     // [0, 2,097,152)
    unsigned short* xTp = (unsigned short*)(ws + 2097152);  // -> [2,097,152, 4,327,424)
    float* ep     = ws + 4327424;                           // 2,097,152 f
    float* scale  = ws + 6424576;                           // 128
    float* shift  = ws + 6424704;                           // 128
    float* biasAll= ws + 6424832;                           // 256 (pad)
    unsigned short* Wb2   = (unsigned short*)(ws + 6425088); // 294,912 sh
    unsigned short* Wqkv  = (unsigned short*)(ws + 6572544); // 20,480 sh
    unsigned short* attnB = (unsigned short*)(ws + 6582784); // 65,536 sh
    unsigned short* qT    = (unsigned short*)(ws + 6615552); // 262,144 sh
    unsigned short* kT    = (unsigned short*)(ws + 6746624); // 262,144 sh
    unsigned short* vB    = (unsigned short*)(ws + 6877696); // 2,097,152 sh
    unsigned short* featB = (unsigned short*)(ws + 7926272); // 2,097,152 sh
    unsigned short* fT    = (unsigned short*)(ws + 8974848); // 2,097,152 sh
    // pamP bf16[4][4][128][4096] = 16.8 MB, aliases convY+xTp+ep (dead by then)
    unsigned short* pamP  = (unsigned short*)ws;

    xt_prep_kernel<<<dim3(4, 64, 4), 256, 0, stream>>>(x, xTp);
    prep_kernel<<<1232, 256, 0, stream>>>(conv_w, q_w, q_b, k_w, k_b, v_w, v_b,
                                          Wb2, Wqkv, biasAll);
    conv_mfma_kernel<<<dim3(2, 64, 4), 256, 0, stream>>>(xTp, Wb2, convY);
    bn_stats_kernel<<<128, 256, 0, stream>>>(convY, bn_g, bn_b, scale, shift);
    bn_apply_kernel<<<dim3(2, 64, 4), 256, 0, stream>>>(convY, scale, shift, featB, fT);
    cam_energy_mfma_kernel<<<dim3(32, 4), 256, 0, stream>>>(featB, ep);
    cam_attn_kernel<<<dim3(128, 4), 128, 0, stream>>>(ep, attnB);
    qkv_mfma_kernel<<<dim3(32, 4), 256, 0, stream>>>(Wqkv, biasAll, fT, qT, kT, vB);
    pam_mfma_kernel<<<dim3(4, 32, 4), 256, 0, stream>>>(qT, kT, vB, pamP);
    combine_kernel<<<dim3(32, 4), 256, 0, stream>>>(attnB, fT, featB, pamP, gca, gpa, out);
}